// Round 2
// baseline (11727.463 us; speedup 1.0000x reference)
//
#include <hip/hip_runtime.h>
#include <stdint.h>

// Exact global median-of-|x| via radix select on fp32 bit pattern, fused with
// the masked copy. thr replicates jnp fp32 semantics: thr = (t*0.1f)/0.1f (RN).
//
// Fast path (ws >= ~49MB):
//   P1: 13-bit LDS hist of bits[30:18]          (read 360MB)
//   P2: masked copy + compact candidate bins B,B+1 to ws  (read 360 + write 360MB)
//   P3: 12-bit + 6-bit select over ~2M candidates (L2-resident)
//   P4: scatter-fix kept candidates (~1M x 4B)
// Fallback: round-1 two-full-hist structure, with kernel zeroing (no rocclr fill).

struct Ctrl {
  unsigned prefix;   // key bits determined so far
  unsigned rank;     // remaining rank within current prefix group
  float    thr;      // final threshold
  unsigned count;    // candidate count (fast path)
};

#define HB 2048
#define HT 256

// ---------------- shared small kernels ----------------

__global__ __launch_bounds__(256) void zero_words_k(unsigned* __restrict__ p, long long nwords) {
  long long i = (long long)blockIdx.x * blockDim.x + threadIdx.x;
  long long s = (long long)gridDim.x * blockDim.x;
  for (; i < nwords; i += s) p[i] = 0u;
}

__global__ __launch_bounds__(64) void init_ctrl_k(Ctrl* c0, unsigned k0,
                                                  Ctrl* c1, unsigned k1) {
  if (threadIdx.x == 0 && blockIdx.x == 0) {
    c0->prefix = 0u; c0->rank = k0; c0->thr = 0.0f; c0->count = 0u;
    c1->prefix = 0u; c1->rank = k1; c1->thr = 0.0f; c1->count = 0u;
  }
}

// Locate rank within a histogram of up to 8192 bins (single block, 1024 thr).
__global__ __launch_bounds__(1024) void scan_stage_k(
    const unsigned* __restrict__ hist, int bits, Ctrl* __restrict__ ctrl)
{
  __shared__ unsigned part[1024];
  const unsigned nb = 1u << bits;
  const unsigned per = (nb + 1023u) >> 10;
  const unsigned t = threadIdx.x;
  const unsigned lo = t * per;
  const unsigned hi = (lo + per < nb) ? (lo + per) : nb;
  const unsigned oldPrefix = ctrl->prefix;
  const unsigned r = ctrl->rank;
  unsigned s = 0;
  for (unsigned j = lo; j < hi; ++j) s += hist[j];
  part[t] = s;
  __syncthreads();
  if (t == 0) {
    unsigned run = 0;
    for (int i = 0; i < 1024; ++i) { unsigned tmp = part[i]; part[i] = run; run += tmp; }
  }
  __syncthreads();
  const unsigned base = part[t];
  if (s > 0 && r >= base && r < base + s) {
    unsigned c = base;
    for (unsigned j = lo; j < hi; ++j) {
      unsigned cnt = hist[j];
      if (r < c + cnt) {
        ctrl->prefix = (oldPrefix << bits) | j;
        ctrl->rank = r - c;
        break;
      }
      c += cnt;
    }
  }
}

__global__ __launch_bounds__(64) void combine_thr_k(Ctrl* a, const Ctrl* b,
                                                    float lw, float hw) {
  if (threadIdx.x == 0 && blockIdx.x == 0) {
    float v0 = __uint_as_float(a->prefix);
    float v1 = __uint_as_float(b->prefix);
    float tq = __fadd_rn(__fmul_rn(v0, lw), __fmul_rn(v1, hw));
    float num = __fmul_rn(tq, 0.1f);
    a->thr = __fdiv_rn(num, 0.1f);
  }
}

// ---------------- fast path ----------------

// Zero the small hist arena (12384 words) + set rank. One block.
__global__ __launch_bounds__(1024) void setup_compact_k(unsigned* arena, unsigned k0) {
  for (unsigned i = threadIdx.x; i < 12384u; i += 1024u) arena[i] = 0u;
  __syncthreads();
  if (threadIdx.x == 0) {
    Ctrl* c = (Ctrl*)arena;
    c->rank = k0;           // prefix/thr/count already zeroed
  }
}

__global__ __launch_bounds__(HT) void hist13_k(
    const uint4* __restrict__ x4, long long n4,
    const unsigned* __restrict__ xs, long long n,
    unsigned* __restrict__ hist)
{
  __shared__ unsigned lh[8192];
  for (unsigned i = threadIdx.x; i < 8192u; i += (unsigned)blockDim.x) lh[i] = 0u;
  __syncthreads();
  const long long stride = (long long)gridDim.x * blockDim.x;
  long long i = (long long)blockIdx.x * blockDim.x + threadIdx.x;
  for (; i < n4; i += stride) {
    uint4 v = x4[i];
    atomicAdd(&lh[(v.x & 0x7fffffffu) >> 18], 1u);
    atomicAdd(&lh[(v.y & 0x7fffffffu) >> 18], 1u);
    atomicAdd(&lh[(v.z & 0x7fffffffu) >> 18], 1u);
    atomicAdd(&lh[(v.w & 0x7fffffffu) >> 18], 1u);
  }
  long long t = n4 * 4 + (long long)blockIdx.x * blockDim.x + threadIdx.x;
  for (; t < n; t += stride)
    atomicAdd(&lh[(xs[t] & 0x7fffffffu) >> 18], 1u);
  __syncthreads();
  for (unsigned j = threadIdx.x; j < 8192u; j += (unsigned)blockDim.x) {
    unsigned cv = lh[j];
    if (cv) atomicAdd(&hist[j], cv);
  }
}

__device__ __forceinline__ float proc_one(
    unsigned raw, unsigned idx, unsigned B, Ctrl* ctrl,
    unsigned* __restrict__ cand_raw, unsigned* __restrict__ cand_idx,
    unsigned cap, unsigned lane, unsigned long long lt)
{
  unsigned key = raw & 0x7fffffffu;
  unsigned b = key >> 18;
  bool cand = (b == B) || (b == B + 1u);
  float v = __uint_as_float(raw);
  float outv = (b > B + 1u) ? v : 0.0f;   // candidates get provisional 0
  unsigned long long m = __ballot(cand ? 1 : 0);
  if (m) {
    int leader = (int)__builtin_ctzll(m);
    unsigned base = 0;
    if ((int)lane == leader) base = atomicAdd(&ctrl->count, (unsigned)__popcll(m));
    base = __shfl(base, leader, 64);
    if (cand) {
      unsigned slot = base + (unsigned)__popcll(m & lt);
      if (slot < cap) { cand_raw[slot] = raw; cand_idx[slot] = idx; }
    }
  }
  return outv;
}

// Fused masked-copy + candidate compaction.
__global__ __launch_bounds__(HT) void pass2_k(
    const uint4* __restrict__ x4, float4* __restrict__ o4, long long n4,
    const unsigned* __restrict__ xs, float* __restrict__ os, long long n,
    Ctrl* __restrict__ ctrl,
    unsigned* __restrict__ cand_raw, unsigned* __restrict__ cand_idx, unsigned cap)
{
  const unsigned B = ctrl->prefix;
  const unsigned lane = (unsigned)(threadIdx.x & 63);
  const unsigned long long lt = (1ull << lane) - 1ull;
  const long long stride = (long long)gridDim.x * blockDim.x;
  long long i = (long long)blockIdx.x * blockDim.x + threadIdx.x;
  for (; i < n4; i += stride) {
    uint4 v = x4[i];
    unsigned bidx = (unsigned)(i * 4);
    float4 w;
    w.x = proc_one(v.x, bidx + 0u, B, ctrl, cand_raw, cand_idx, cap, lane, lt);
    w.y = proc_one(v.y, bidx + 1u, B, ctrl, cand_raw, cand_idx, cap, lane, lt);
    w.z = proc_one(v.z, bidx + 2u, B, ctrl, cand_raw, cand_idx, cap, lane, lt);
    w.w = proc_one(v.w, bidx + 3u, B, ctrl, cand_raw, cand_idx, cap, lane, lt);
    o4[i] = w;
  }
  long long t = n4 * 4 + (long long)blockIdx.x * blockDim.x + threadIdx.x;
  for (; t < n; t += stride) {
    unsigned raw = xs[t];
    os[t] = proc_one(raw, (unsigned)t, B, ctrl, cand_raw, cand_idx, cap, lane, lt);
  }
}

// LDS-aggregated hist over the compacted candidates (count read from ctrl).
__global__ __launch_bounds__(HT) void cand_hist_k(
    const unsigned* __restrict__ cand_raw, const Ctrl* __restrict__ ctrl,
    unsigned* __restrict__ hist, int shift, int bits, unsigned cap)
{
  __shared__ unsigned lh[4096];
  const unsigned nb = 1u << bits;
  for (unsigned i = threadIdx.x; i < nb; i += (unsigned)blockDim.x) lh[i] = 0u;
  __syncthreads();
  unsigned n = ctrl->count; if (n > cap) n = cap;
  const unsigned prefix = ctrl->prefix;
  const int top = shift + bits;
  const unsigned m = nb - 1u;
  const unsigned stride = gridDim.x * blockDim.x;
  for (unsigned t = blockIdx.x * blockDim.x + threadIdx.x; t < n; t += stride) {
    unsigned key = cand_raw[t] & 0x7fffffffu;
    if ((key >> top) == prefix) atomicAdd(&lh[(key >> shift) & m], 1u);
  }
  __syncthreads();
  for (unsigned j = threadIdx.x; j < nb; j += (unsigned)blockDim.x) {
    unsigned cv = lh[j];
    if (cv) atomicAdd(&hist[j], cv);
  }
}

// Scatter-fix: write back the candidates that survive the exact threshold test.
__global__ __launch_bounds__(HT) void fixup_k(
    const unsigned* __restrict__ cand_raw, const unsigned* __restrict__ cand_idx,
    const Ctrl* __restrict__ ctrl, float* __restrict__ out, unsigned cap)
{
  const float thr = ctrl->thr;
  unsigned n = ctrl->count; if (n > cap) n = cap;
  const unsigned stride = gridDim.x * blockDim.x;
  for (unsigned t = blockIdx.x * blockDim.x + threadIdx.x; t < n; t += stride) {
    unsigned raw = cand_raw[t];
    float v = __uint_as_float(raw);
    if (fabsf(v) > thr) out[cand_idx[t]] = v;
  }
}

// ---------------- fallback path (round-1 structure) ----------------

__global__ __launch_bounds__(HT) void hist_stage_k(
    const uint4* __restrict__ x4, long long n4,
    const unsigned* __restrict__ xs, long long n,
    unsigned* __restrict__ hist,
    const Ctrl* __restrict__ ctrl,
    int shift, int bits)
{
  __shared__ unsigned lh[4096];
  const unsigned nb = 1u << bits;
  const bool lds = (bits <= 12);
  if (lds) {
    for (unsigned i = threadIdx.x; i < nb; i += blockDim.x) lh[i] = 0u;
    __syncthreads();
  }
  const unsigned prefix = ctrl->prefix;
  const int top = shift + bits;
  const unsigned m = nb - 1u;
  const long long stride = (long long)gridDim.x * blockDim.x;
  long long i = (long long)blockIdx.x * blockDim.x + threadIdx.x;
  for (; i < n4; i += stride) {
    uint4 v = x4[i];
    unsigned a = v.x & 0x7fffffffu;
    unsigned b = v.y & 0x7fffffffu;
    unsigned c = v.z & 0x7fffffffu;
    unsigned d = v.w & 0x7fffffffu;
    if (lds) {
      if ((a >> top) == prefix) atomicAdd(&lh[(a >> shift) & m], 1u);
      if ((b >> top) == prefix) atomicAdd(&lh[(b >> shift) & m], 1u);
      if ((c >> top) == prefix) atomicAdd(&lh[(c >> shift) & m], 1u);
      if ((d >> top) == prefix) atomicAdd(&lh[(d >> shift) & m], 1u);
    } else {
      if ((a >> top) == prefix) atomicAdd(&hist[(a >> shift) & m], 1u);
      if ((b >> top) == prefix) atomicAdd(&hist[(b >> shift) & m], 1u);
      if ((c >> top) == prefix) atomicAdd(&hist[(c >> shift) & m], 1u);
      if ((d >> top) == prefix) atomicAdd(&hist[(d >> shift) & m], 1u);
    }
  }
  long long t = n4 * 4 + (long long)blockIdx.x * blockDim.x + threadIdx.x;
  for (; t < n; t += stride) {
    unsigned u = xs[t] & 0x7fffffffu;
    if ((u >> top) == prefix) {
      if (lds) atomicAdd(&lh[(u >> shift) & m], 1u);
      else     atomicAdd(&hist[(u >> shift) & m], 1u);
    }
  }
  if (lds) {
    __syncthreads();
    for (unsigned j = threadIdx.x; j < nb; j += blockDim.x) {
      unsigned cv = lh[j];
      if (cv) atomicAdd(&hist[j], cv);
    }
  }
}

__global__ __launch_bounds__(256) void scan_big1_k(
    const unsigned* __restrict__ hist, unsigned* __restrict__ chunkSums)
{
  __shared__ unsigned red[256];
  const unsigned base = blockIdx.x * 1024u;
  unsigned s = 0;
  for (unsigned i = threadIdx.x; i < 1024u; i += 256u) s += hist[base + i];
  red[threadIdx.x] = s;
  __syncthreads();
  for (unsigned off = 128; off > 0; off >>= 1) {
    if (threadIdx.x < off) red[threadIdx.x] += red[threadIdx.x + off];
    __syncthreads();
  }
  if (threadIdx.x == 0) chunkSums[blockIdx.x] = red[0];
}

__global__ __launch_bounds__(1024) void scan_big2_k(
    const unsigned* __restrict__ hist, const unsigned* __restrict__ chunkSums,
    Ctrl* __restrict__ ctrl)
{
  __shared__ unsigned cs[512];
  __shared__ unsigned sc[1024];
  __shared__ unsigned sel[2];
  const unsigned t = threadIdx.x;
  const unsigned oldPrefix = ctrl->prefix;
  const unsigned r = ctrl->rank;
  if (t < 512) cs[t] = chunkSums[t];
  __syncthreads();
  if (t == 0) {
    unsigned run = 0;
    unsigned ci = 0, cb = 0;
    for (int i = 0; i < 512; ++i) {
      unsigned cnt = cs[i];
      if (r >= run && r < run + cnt) { ci = (unsigned)i; cb = run; }
      run += cnt;
    }
    sel[0] = ci; sel[1] = cb;
  }
  __syncthreads();
  const unsigned ci = sel[0];
  const unsigned cb = sel[1];
  const unsigned val = hist[ci * 1024u + t];
  sc[t] = val;
  __syncthreads();
  for (unsigned off = 1; off < 1024; off <<= 1) {
    unsigned add = (t >= off) ? sc[t - off] : 0u;
    __syncthreads();
    sc[t] += add;
    __syncthreads();
  }
  const unsigned incl = sc[t];
  const unsigned excl = incl - val;
  const unsigned rr = r - cb;
  if (val > 0 && rr >= excl && rr < incl) {
    unsigned j = ci * 1024u + t;
    ctrl->prefix = (oldPrefix << 19) | j;
    ctrl->rank = rr - excl;
  }
}

__global__ __launch_bounds__(HT) void mask_k(
    const float4* __restrict__ x4, float4* __restrict__ o4, long long n4,
    const float* __restrict__ xs, float* __restrict__ os, long long n,
    const Ctrl* __restrict__ ctrl)
{
  const float thr = ctrl->thr;
  const long long stride = (long long)gridDim.x * blockDim.x;
  long long i = (long long)blockIdx.x * blockDim.x + threadIdx.x;
  for (; i < n4; i += stride) {
    float4 v = x4[i];
    float4 w;
    w.x = (fabsf(v.x) <= thr) ? 0.0f : v.x;
    w.y = (fabsf(v.y) <= thr) ? 0.0f : v.y;
    w.z = (fabsf(v.z) <= thr) ? 0.0f : v.z;
    w.w = (fabsf(v.w) <= thr) ? 0.0f : v.w;
    o4[i] = w;
  }
  long long t = n4 * 4 + (long long)blockIdx.x * blockDim.x + threadIdx.x;
  for (; t < n; t += stride) {
    float v = xs[t];
    os[t] = (fabsf(v) <= thr) ? 0.0f : v;
  }
}

// ---------------- launch ----------------

extern "C" void kernel_launch(void* const* d_in, const int* in_sizes, int n_in,
                              void* d_out, int out_size, void* d_ws, size_t ws_size,
                              hipStream_t stream)
{
  const float* x = (const float*)d_in[0];
  const long long N = (long long)in_sizes[0];
  const long long n4 = N >> 2;
  const uint4* x4 = (const uint4*)x;
  const unsigned* xbits = (const unsigned*)x;

  // jnp.quantile fp32 index math: idx = 0.5f * f32(N-1).
  float idxf = 0.5f * (float)(N - 1);
  float lowf = floorf(idxf);
  float highf = ceilf(idxf);
  float hw = idxf - lowf;
  float lw = 1.0f - hw;
  unsigned k0 = (unsigned)lowf;
  unsigned k1 = (unsigned)highf;
  int dual = (hw != 0.0f);
  if (!dual) k1 = k0;

  // Fast-path workspace: arena hists [0,64KB), cand_raw CAP*4, cand_idx CAP*4.
  const unsigned CAP = 6u * 1024u * 1024u;          // 6M candidates (3x margin)
  const size_t needC = 65536 + (size_t)CAP * 8;     // ~48.07 MB

  if (!dual && ws_size >= needC) {
    unsigned* arena = (unsigned*)d_ws;
    Ctrl* c0 = (Ctrl*)arena;
    unsigned* h1 = arena + 32;          // 8192 bins
    unsigned* h2 = arena + 32 + 8192;   // 4096 bins
    unsigned* h3 = arena + 32 + 8192 + 4096; // 64 bins
    unsigned* cand_raw = (unsigned*)((char*)d_ws + 65536);
    unsigned* cand_idx = cand_raw + CAP;

    setup_compact_k<<<1, 1024, 0, stream>>>(arena, k0);
    hist13_k<<<HB, HT, 0, stream>>>(x4, n4, xbits, N, h1);
    scan_stage_k<<<1, 1024, 0, stream>>>(h1, 13, c0);
    pass2_k<<<HB, HT, 0, stream>>>(x4, (float4*)d_out, n4, xbits, (float*)d_out, N,
                                   c0, cand_raw, cand_idx, CAP);
    cand_hist_k<<<256, HT, 0, stream>>>(cand_raw, c0, h2, 6, 12, CAP);
    scan_stage_k<<<1, 1024, 0, stream>>>(h2, 12, c0);
    cand_hist_k<<<256, HT, 0, stream>>>(cand_raw, c0, h3, 0, 6, CAP);
    scan_stage_k<<<1, 1024, 0, stream>>>(h3, 6, c0);
    combine_thr_k<<<1, 64, 0, stream>>>(c0, c0, lw, hw);
    fixup_k<<<512, HT, 0, stream>>>(cand_raw, cand_idx, c0, (float*)d_out, CAP);
    return;
  }

  // ---------- fallback: round-1 pathA with kernel zeroing ----------
  const size_t needA = 65536 + (size_t)(1u << 19) * 4;  // 2,162,688
  char* wsb = (char*)d_ws;
  char* arena = (ws_size >= needA) ? wsb : (char*)d_out;  // d_out fully rewritten at end
  Ctrl* c0 = (ws_size >= 128) ? (Ctrl*)wsb : (Ctrl*)arena;
  Ctrl* c1 = c0 + 1;
  unsigned* chunkSums = (unsigned*)(arena + 128);
  unsigned* h1 = (unsigned*)(arena + 4096);
  unsigned* h2 = (unsigned*)(arena + 65536);
  const long long zwords = (long long)(needA - 4096) / 4;

  zero_words_k<<<512, 256, 0, stream>>>((unsigned*)(arena + 4096), zwords);
  init_ctrl_k<<<1, 64, 0, stream>>>(c0, k0, (dual ? c1 : c0), k1);

  const int nchain = dual ? 2 : 1;
  for (int chain = 0; chain < nchain; ++chain) {
    Ctrl* cc = chain ? c1 : c0;
    if (chain) zero_words_k<<<512, 256, 0, stream>>>((unsigned*)(arena + 4096), zwords);
    hist_stage_k<<<HB, HT, 0, stream>>>(x4, n4, xbits, N, h1, cc, 19, 12);
    scan_stage_k<<<1, 1024, 0, stream>>>(h1, 12, cc);
    hist_stage_k<<<HB, HT, 0, stream>>>(x4, n4, xbits, N, h2, cc, 0, 19);
    scan_big1_k<<<512, 256, 0, stream>>>(h2, chunkSums);
    scan_big2_k<<<1, 1024, 0, stream>>>(h2, chunkSums, cc);
  }
  combine_thr_k<<<1, 64, 0, stream>>>(c0, (dual ? c1 : c0), lw, hw);
  mask_k<<<HB, HT, 0, stream>>>((const float4*)x, (float4*)d_out, n4,
                                x, (float*)d_out, N, c0);
}

// Round 3
// 391.693 us; speedup vs baseline: 29.9405x; 29.9405x over previous
//
#include <hip/hip_runtime.h>
#include <stdint.h>

// Exact global median-of-|x| via radix select on fp32 bit pattern, fused with
// the masked copy. thr replicates jnp fp32 semantics: thr = (t*0.1f)/0.1f (RN).
//
// Fast path (ws >= ~35MB):
//   P1: 13-bit LDS hist of bits[30:18]                        (read 360MB)
//   P2: masked copy + SEGMENTED compaction of bins {B, B+1}   (read 360 + write ~375MB)
//       - per-block private segment, LDS counter, zero cross-block atomics
//   P3: 12-bit + 6-bit select over ~1.7M compacted candidates (L2-resident)
//   P4: scatter-fix kept candidates (~0.9M x 4B)
// Fallback: two-full-hist structure with kernel zeroing.

struct Ctrl {
  unsigned prefix;   // key bits determined so far
  unsigned rank;     // remaining rank within current prefix group
  float    thr;      // final threshold
  unsigned ovf;      // overflow-region candidate count (fast path)
};

#define HB 2048
#define HT 256
#define SEGS 2048u
#define SEGCAP 2048u
#define OCAP 65536u

// Arena word offsets (all zeroed by setup_compact_k):
//   [0..4)      Ctrl
//   [32..8224)  h1 (8192 bins)
//   [8224..12320) h2 (4096 bins)
//   [12320..12384) h3 (64 bins)
//   [12384..14433) seg_cnt (SEGS+1)
#define ARENA_WORDS 16384u

// ---------------- shared small kernels ----------------

__global__ __launch_bounds__(256) void zero_words_k(unsigned* __restrict__ p, long long nwords) {
  long long i = (long long)blockIdx.x * blockDim.x + threadIdx.x;
  long long s = (long long)gridDim.x * blockDim.x;
  for (; i < nwords; i += s) p[i] = 0u;
}

__global__ __launch_bounds__(64) void init_ctrl_k(Ctrl* c0, unsigned k0,
                                                  Ctrl* c1, unsigned k1) {
  if (threadIdx.x == 0 && blockIdx.x == 0) {
    c0->prefix = 0u; c0->rank = k0; c0->thr = 0.0f; c0->ovf = 0u;
    c1->prefix = 0u; c1->rank = k1; c1->thr = 0.0f; c1->ovf = 0u;
  }
}

// Locate rank within a histogram of up to 8192 bins (single block, 1024 thr).
__global__ __launch_bounds__(1024) void scan_stage_k(
    const unsigned* __restrict__ hist, int bits, Ctrl* __restrict__ ctrl)
{
  __shared__ unsigned part[1024];
  const unsigned nb = 1u << bits;
  const unsigned per = (nb + 1023u) >> 10;
  const unsigned t = threadIdx.x;
  const unsigned lo = t * per;
  const unsigned hi = (lo + per < nb) ? (lo + per) : nb;
  const unsigned oldPrefix = ctrl->prefix;
  const unsigned r = ctrl->rank;
  unsigned s = 0;
  for (unsigned j = lo; j < hi; ++j) s += hist[j];
  part[t] = s;
  __syncthreads();
  if (t == 0) {
    unsigned run = 0;
    for (int i = 0; i < 1024; ++i) { unsigned tmp = part[i]; part[i] = run; run += tmp; }
  }
  __syncthreads();
  const unsigned base = part[t];
  if (s > 0 && r >= base && r < base + s) {
    unsigned c = base;
    for (unsigned j = lo; j < hi; ++j) {
      unsigned cnt = hist[j];
      if (r < c + cnt) {
        ctrl->prefix = (oldPrefix << bits) | j;
        ctrl->rank = r - c;
        break;
      }
      c += cnt;
    }
  }
}

__global__ __launch_bounds__(64) void combine_thr_k(Ctrl* a, const Ctrl* b,
                                                    float lw, float hw) {
  if (threadIdx.x == 0 && blockIdx.x == 0) {
    float v0 = __uint_as_float(a->prefix);
    float v1 = __uint_as_float(b->prefix);
    float tq = __fadd_rn(__fmul_rn(v0, lw), __fmul_rn(v1, hw));
    float num = __fmul_rn(tq, 0.1f);
    a->thr = __fdiv_rn(num, 0.1f);
  }
}

// ---------------- fast path ----------------

__global__ __launch_bounds__(1024) void setup_compact_k(unsigned* arena, unsigned k0) {
  for (unsigned i = threadIdx.x; i < ARENA_WORDS; i += 1024u) arena[i] = 0u;
  __syncthreads();
  if (threadIdx.x == 0) {
    Ctrl* c = (Ctrl*)arena;
    c->rank = k0;           // prefix/thr/ovf already zeroed
  }
}

__global__ __launch_bounds__(HT) void hist13_k(
    const uint4* __restrict__ x4, long long n4,
    const unsigned* __restrict__ xs, long long n,
    unsigned* __restrict__ hist)
{
  __shared__ unsigned lh[8192];
  for (unsigned i = threadIdx.x; i < 8192u; i += (unsigned)blockDim.x) lh[i] = 0u;
  __syncthreads();
  const long long stride = (long long)gridDim.x * blockDim.x;
  long long i = (long long)blockIdx.x * blockDim.x + threadIdx.x;
  for (; i < n4; i += stride) {
    uint4 v = x4[i];
    atomicAdd(&lh[(v.x & 0x7fffffffu) >> 18], 1u);
    atomicAdd(&lh[(v.y & 0x7fffffffu) >> 18], 1u);
    atomicAdd(&lh[(v.z & 0x7fffffffu) >> 18], 1u);
    atomicAdd(&lh[(v.w & 0x7fffffffu) >> 18], 1u);
  }
  long long t = n4 * 4 + (long long)blockIdx.x * blockDim.x + threadIdx.x;
  for (; t < n; t += stride)
    atomicAdd(&lh[(xs[t] & 0x7fffffffu) >> 18], 1u);
  __syncthreads();
  for (unsigned j = threadIdx.x; j < 8192u; j += (unsigned)blockDim.x) {
    unsigned cv = lh[j];
    if (cv) atomicAdd(&hist[j], cv);
  }
}

// Fused masked-copy + segmented candidate compaction. No cross-block atomics
// on the hot path: per-block LDS counter + private global segment.
__global__ __launch_bounds__(HT) void pass2_k(
    const uint4* __restrict__ x4, float4* __restrict__ o4, long long n4,
    const unsigned* __restrict__ xs, float* __restrict__ os, long long n,
    Ctrl* __restrict__ ctrl, unsigned* __restrict__ seg_cnt,
    uint2* __restrict__ cand)
{
  __shared__ unsigned lcnt;
  if (threadIdx.x == 0) lcnt = 0u;
  __syncthreads();
  const unsigned B = ctrl->prefix;
  uint2* __restrict__ seg = cand + (size_t)blockIdx.x * SEGCAP;
  uint2* __restrict__ ovf = cand + (size_t)SEGS * SEGCAP;
  const long long stride = (long long)gridDim.x * blockDim.x;
  long long i = (long long)blockIdx.x * blockDim.x + threadIdx.x;
  for (; i < n4; i += stride) {
    uint4 v = x4[i];
    unsigned bidx = (unsigned)(i * 4);
    float4 w;
    #pragma unroll
    for (int c = 0; c < 4; ++c) {
      unsigned raw = (&v.x)[c];
      unsigned b = (raw & 0x7fffffffu) >> 18;
      float val = __uint_as_float(raw);
      (&w.x)[c] = (b > B + 1u) ? val : 0.0f;
      if (b == B || b == B + 1u) {
        unsigned pos = atomicAdd(&lcnt, 1u);
        uint2 e; e.x = raw; e.y = bidx + (unsigned)c;
        if (pos < SEGCAP) seg[pos] = e;
        else {
          unsigned opos = atomicAdd(&ctrl->ovf, 1u);
          if (opos < OCAP) ovf[opos] = e;
        }
      }
    }
    o4[i] = w;
  }
  long long t = n4 * 4 + (long long)blockIdx.x * blockDim.x + threadIdx.x;
  for (; t < n; t += stride) {
    unsigned raw = xs[t];
    unsigned b = (raw & 0x7fffffffu) >> 18;
    float val = __uint_as_float(raw);
    os[t] = (b > B + 1u) ? val : 0.0f;
    if (b == B || b == B + 1u) {
      unsigned pos = atomicAdd(&lcnt, 1u);
      uint2 e; e.x = raw; e.y = (unsigned)t;
      if (pos < SEGCAP) seg[pos] = e;
      else {
        unsigned opos = atomicAdd(&ctrl->ovf, 1u);
        if (opos < OCAP) ovf[opos] = e;
      }
    }
  }
  __syncthreads();
  if (threadIdx.x == 0)
    seg_cnt[blockIdx.x] = (lcnt < SEGCAP) ? lcnt : SEGCAP;
}

// LDS-aggregated hist over segmented candidates. One block per segment;
// block 0 additionally sweeps the overflow region.
__global__ __launch_bounds__(HT) void cand_hist_k(
    const uint2* __restrict__ cand, const unsigned* __restrict__ seg_cnt,
    const Ctrl* __restrict__ ctrl, unsigned* __restrict__ hist,
    int shift, int bits)
{
  __shared__ unsigned lh[4096];
  const unsigned nb = 1u << bits;
  for (unsigned i = threadIdx.x; i < nb; i += (unsigned)blockDim.x) lh[i] = 0u;
  __syncthreads();
  const unsigned prefix = ctrl->prefix;
  const int top = shift + bits;
  const unsigned m = nb - 1u;
  const uint2* __restrict__ seg = cand + (size_t)blockIdx.x * SEGCAP;
  unsigned cnt = seg_cnt[blockIdx.x];
  for (unsigned t = threadIdx.x; t < cnt; t += (unsigned)blockDim.x) {
    unsigned key = seg[t].x & 0x7fffffffu;
    if ((key >> top) == prefix) atomicAdd(&lh[(key >> shift) & m], 1u);
  }
  if (blockIdx.x == 0) {
    unsigned oc = ctrl->ovf; if (oc > OCAP) oc = OCAP;
    const uint2* __restrict__ ovf = cand + (size_t)SEGS * SEGCAP;
    for (unsigned t = threadIdx.x; t < oc; t += (unsigned)blockDim.x) {
      unsigned key = ovf[t].x & 0x7fffffffu;
      if ((key >> top) == prefix) atomicAdd(&lh[(key >> shift) & m], 1u);
    }
  }
  __syncthreads();
  for (unsigned j = threadIdx.x; j < nb; j += (unsigned)blockDim.x) {
    unsigned cv = lh[j];
    if (cv) atomicAdd(&hist[j], cv);
  }
}

// Scatter-fix: write back candidates that survive the exact threshold test.
__global__ __launch_bounds__(HT) void fixup_k(
    const uint2* __restrict__ cand, const unsigned* __restrict__ seg_cnt,
    const Ctrl* __restrict__ ctrl, float* __restrict__ out)
{
  const float thr = ctrl->thr;
  const uint2* __restrict__ seg = cand + (size_t)blockIdx.x * SEGCAP;
  unsigned cnt = seg_cnt[blockIdx.x];
  for (unsigned t = threadIdx.x; t < cnt; t += (unsigned)blockDim.x) {
    uint2 e = seg[t];
    float v = __uint_as_float(e.x);
    if (fabsf(v) > thr) out[e.y] = v;
  }
  if (blockIdx.x == 0) {
    unsigned oc = ctrl->ovf; if (oc > OCAP) oc = OCAP;
    const uint2* __restrict__ ovf = cand + (size_t)SEGS * SEGCAP;
    for (unsigned t = threadIdx.x; t < oc; t += (unsigned)blockDim.x) {
      uint2 e = ovf[t];
      float v = __uint_as_float(e.x);
      if (fabsf(v) > thr) out[e.y] = v;
    }
  }
}

// ---------------- fallback path ----------------

__global__ __launch_bounds__(HT) void hist_stage_k(
    const uint4* __restrict__ x4, long long n4,
    const unsigned* __restrict__ xs, long long n,
    unsigned* __restrict__ hist,
    const Ctrl* __restrict__ ctrl,
    int shift, int bits)
{
  __shared__ unsigned lh[4096];
  const unsigned nb = 1u << bits;
  const bool lds = (bits <= 12);
  if (lds) {
    for (unsigned i = threadIdx.x; i < nb; i += blockDim.x) lh[i] = 0u;
    __syncthreads();
  }
  const unsigned prefix = ctrl->prefix;
  const int top = shift + bits;
  const unsigned m = nb - 1u;
  const long long stride = (long long)gridDim.x * blockDim.x;
  long long i = (long long)blockIdx.x * blockDim.x + threadIdx.x;
  for (; i < n4; i += stride) {
    uint4 v = x4[i];
    unsigned a = v.x & 0x7fffffffu;
    unsigned b = v.y & 0x7fffffffu;
    unsigned c = v.z & 0x7fffffffu;
    unsigned d = v.w & 0x7fffffffu;
    if (lds) {
      if ((a >> top) == prefix) atomicAdd(&lh[(a >> shift) & m], 1u);
      if ((b >> top) == prefix) atomicAdd(&lh[(b >> shift) & m], 1u);
      if ((c >> top) == prefix) atomicAdd(&lh[(c >> shift) & m], 1u);
      if ((d >> top) == prefix) atomicAdd(&lh[(d >> shift) & m], 1u);
    } else {
      if ((a >> top) == prefix) atomicAdd(&hist[(a >> shift) & m], 1u);
      if ((b >> top) == prefix) atomicAdd(&hist[(b >> shift) & m], 1u);
      if ((c >> top) == prefix) atomicAdd(&hist[(c >> shift) & m], 1u);
      if ((d >> top) == prefix) atomicAdd(&hist[(d >> shift) & m], 1u);
    }
  }
  long long t = n4 * 4 + (long long)blockIdx.x * blockDim.x + threadIdx.x;
  for (; t < n; t += stride) {
    unsigned u = xs[t] & 0x7fffffffu;
    if ((u >> top) == prefix) {
      if (lds) atomicAdd(&lh[(u >> shift) & m], 1u);
      else     atomicAdd(&hist[(u >> shift) & m], 1u);
    }
  }
  if (lds) {
    __syncthreads();
    for (unsigned j = threadIdx.x; j < nb; j += blockDim.x) {
      unsigned cv = lh[j];
      if (cv) atomicAdd(&hist[j], cv);
    }
  }
}

__global__ __launch_bounds__(256) void scan_big1_k(
    const unsigned* __restrict__ hist, unsigned* __restrict__ chunkSums)
{
  __shared__ unsigned red[256];
  const unsigned base = blockIdx.x * 1024u;
  unsigned s = 0;
  for (unsigned i = threadIdx.x; i < 1024u; i += 256u) s += hist[base + i];
  red[threadIdx.x] = s;
  __syncthreads();
  for (unsigned off = 128; off > 0; off >>= 1) {
    if (threadIdx.x < off) red[threadIdx.x] += red[threadIdx.x + off];
    __syncthreads();
  }
  if (threadIdx.x == 0) chunkSums[blockIdx.x] = red[0];
}

__global__ __launch_bounds__(1024) void scan_big2_k(
    const unsigned* __restrict__ hist, const unsigned* __restrict__ chunkSums,
    Ctrl* __restrict__ ctrl)
{
  __shared__ unsigned cs[512];
  __shared__ unsigned sc[1024];
  __shared__ unsigned sel[2];
  const unsigned t = threadIdx.x;
  const unsigned oldPrefix = ctrl->prefix;
  const unsigned r = ctrl->rank;
  if (t < 512) cs[t] = chunkSums[t];
  __syncthreads();
  if (t == 0) {
    unsigned run = 0;
    unsigned ci = 0, cb = 0;
    for (int i = 0; i < 512; ++i) {
      unsigned cnt = cs[i];
      if (r >= run && r < run + cnt) { ci = (unsigned)i; cb = run; }
      run += cnt;
    }
    sel[0] = ci; sel[1] = cb;
  }
  __syncthreads();
  const unsigned ci = sel[0];
  const unsigned cb = sel[1];
  const unsigned val = hist[ci * 1024u + t];
  sc[t] = val;
  __syncthreads();
  for (unsigned off = 1; off < 1024; off <<= 1) {
    unsigned add = (t >= off) ? sc[t - off] : 0u;
    __syncthreads();
    sc[t] += add;
    __syncthreads();
  }
  const unsigned incl = sc[t];
  const unsigned excl = incl - val;
  const unsigned rr = r - cb;
  if (val > 0 && rr >= excl && rr < incl) {
    unsigned j = ci * 1024u + t;
    ctrl->prefix = (oldPrefix << 19) | j;
    ctrl->rank = rr - excl;
  }
}

__global__ __launch_bounds__(HT) void mask_k(
    const float4* __restrict__ x4, float4* __restrict__ o4, long long n4,
    const float* __restrict__ xs, float* __restrict__ os, long long n,
    const Ctrl* __restrict__ ctrl)
{
  const float thr = ctrl->thr;
  const long long stride = (long long)gridDim.x * blockDim.x;
  long long i = (long long)blockIdx.x * blockDim.x + threadIdx.x;
  for (; i < n4; i += stride) {
    float4 v = x4[i];
    float4 w;
    w.x = (fabsf(v.x) <= thr) ? 0.0f : v.x;
    w.y = (fabsf(v.y) <= thr) ? 0.0f : v.y;
    w.z = (fabsf(v.z) <= thr) ? 0.0f : v.z;
    w.w = (fabsf(v.w) <= thr) ? 0.0f : v.w;
    o4[i] = w;
  }
  long long t = n4 * 4 + (long long)blockIdx.x * blockDim.x + threadIdx.x;
  for (; t < n; t += stride) {
    float v = xs[t];
    os[t] = (fabsf(v) <= thr) ? 0.0f : v;
  }
}

// ---------------- launch ----------------

extern "C" void kernel_launch(void* const* d_in, const int* in_sizes, int n_in,
                              void* d_out, int out_size, void* d_ws, size_t ws_size,
                              hipStream_t stream)
{
  const float* x = (const float*)d_in[0];
  const long long N = (long long)in_sizes[0];
  const long long n4 = N >> 2;
  const uint4* x4 = (const uint4*)x;
  const unsigned* xbits = (const unsigned*)x;

  // jnp.quantile fp32 index math: idx = 0.5f * f32(N-1).
  float idxf = 0.5f * (float)(N - 1);
  float lowf = floorf(idxf);
  float highf = ceilf(idxf);
  float hw = idxf - lowf;
  float lw = 1.0f - hw;
  unsigned k0 = (unsigned)lowf;
  unsigned k1 = (unsigned)highf;
  int dual = (hw != 0.0f);
  if (!dual) k1 = k0;

  // Fast-path workspace: arena 64KB + cand (SEGS*SEGCAP + OCAP) uint2.
  const size_t needC = 65536 + ((size_t)SEGS * SEGCAP + OCAP) * 8;  // ~34.1 MB

  if (!dual && N < (1ll << 32) && ws_size >= needC) {
    unsigned* arena = (unsigned*)d_ws;
    Ctrl* c0 = (Ctrl*)arena;
    unsigned* h1 = arena + 32;
    unsigned* h2 = arena + 32 + 8192;
    unsigned* h3 = arena + 32 + 8192 + 4096;
    unsigned* seg_cnt = arena + 32 + 8192 + 4096 + 64;
    uint2* cand = (uint2*)((char*)d_ws + 65536);

    setup_compact_k<<<1, 1024, 0, stream>>>(arena, k0);
    hist13_k<<<HB, HT, 0, stream>>>(x4, n4, xbits, N, h1);
    scan_stage_k<<<1, 1024, 0, stream>>>(h1, 13, c0);
    pass2_k<<<SEGS, HT, 0, stream>>>(x4, (float4*)d_out, n4, xbits, (float*)d_out, N,
                                     c0, seg_cnt, cand);
    cand_hist_k<<<SEGS, HT, 0, stream>>>(cand, seg_cnt, c0, h2, 6, 12);
    scan_stage_k<<<1, 1024, 0, stream>>>(h2, 12, c0);
    cand_hist_k<<<SEGS, HT, 0, stream>>>(cand, seg_cnt, c0, h3, 0, 6);
    scan_stage_k<<<1, 1024, 0, stream>>>(h3, 6, c0);
    combine_thr_k<<<1, 64, 0, stream>>>(c0, c0, lw, hw);
    fixup_k<<<SEGS, HT, 0, stream>>>(cand, seg_cnt, c0, (float*)d_out);
    return;
  }

  // ---------- fallback: two-full-hist structure with kernel zeroing ----------
  const size_t needA = 65536 + (size_t)(1u << 19) * 4;  // 2,162,688
  char* wsb = (char*)d_ws;
  char* arena = (ws_size >= needA) ? wsb : (char*)d_out;  // d_out fully rewritten at end
  Ctrl* c0 = (ws_size >= 128) ? (Ctrl*)wsb : (Ctrl*)arena;
  Ctrl* c1 = c0 + 1;
  unsigned* chunkSums = (unsigned*)(arena + 128);
  unsigned* h1 = (unsigned*)(arena + 4096);
  unsigned* h2 = (unsigned*)(arena + 65536);
  const long long zwords = (long long)(needA - 4096) / 4;

  zero_words_k<<<512, 256, 0, stream>>>((unsigned*)(arena + 4096), zwords);
  init_ctrl_k<<<1, 64, 0, stream>>>(c0, k0, (dual ? c1 : c0), k1);

  const int nchain = dual ? 2 : 1;
  for (int chain = 0; chain < nchain; ++chain) {
    Ctrl* cc = chain ? c1 : c0;
    if (chain) zero_words_k<<<512, 256, 0, stream>>>((unsigned*)(arena + 4096), zwords);
    hist_stage_k<<<HB, HT, 0, stream>>>(x4, n4, xbits, N, h1, cc, 19, 12);
    scan_stage_k<<<1, 1024, 0, stream>>>(h1, 12, cc);
    hist_stage_k<<<HB, HT, 0, stream>>>(x4, n4, xbits, N, h2, cc, 0, 19);
    scan_big1_k<<<512, 256, 0, stream>>>(h2, chunkSums);
    scan_big2_k<<<1, 1024, 0, stream>>>(h2, chunkSums, cc);
  }
  combine_thr_k<<<1, 64, 0, stream>>>(c0, (dual ? c1 : c0), lw, hw);
  mask_k<<<HB, HT, 0, stream>>>((const float4*)x, (float4*)d_out, n4,
                                x, (float*)d_out, N, c0);
}

// Round 5
// 335.937 us; speedup vs baseline: 34.9097x; 1.1660x over previous
//
#include <hip/hip_runtime.h>
#include <stdint.h>

// Exact global median-of-|x| via radix select on fp32 bit pattern, fused with
// the masked copy. thr replicates jnp fp32 semantics: thr = (t*0.1f)/0.1f (RN).
//
// Fast path (ws >= ~35MB):
//   P1: 13-bit LDS hist of bits[30:18], dual bank-shifted copies   (read 360MB)
//   P2: masked copy (reverse order, nontemporal stores) +
//       SEGMENTED compaction of bins {B,B+1}            (read 360* + write ~375MB)
//       (*partially served by Infinity Cache from P1's tail)
//   P3: single 18-bit global-atomic refine over ~1.7M candidates (L2-resident)
//   P4: scatter-fix kept candidates
// Fallback: two-full-hist structure with kernel zeroing.

struct Ctrl {
  unsigned prefix;   // key bits determined so far
  unsigned rank;     // remaining rank within current prefix group
  float    thr;      // final threshold
  unsigned ovf;      // overflow-region candidate count (fast path)
};

typedef float fx4 __attribute__((ext_vector_type(4)));  // native vec for nt-store

#define SEGS 2048u
#define SEGCAP 2048u
#define OCAP 65536u

// Arena word offsets:
//   [0..4)          Ctrl
//   [32..8224)      h1  (8192 bins)
//   [8224..10272)   seg_cnt (2048)
//   [10272..10528)  chunkSums (256)
//   [16384..278528) h18 (262144 bins)
#define W_H1     32u
#define W_SEGCNT 8224u
#define W_CHUNK  10272u
#define W_H18    16384u
#define ARENA_WORDS 278528u
#define CAND_BYTE_OFF (2u*1024u*1024u)

// ---------------- shared small kernels ----------------

__global__ __launch_bounds__(256) void zero_words_k(unsigned* __restrict__ p, long long nwords) {
  long long i = (long long)blockIdx.x * blockDim.x + threadIdx.x;
  long long s = (long long)gridDim.x * blockDim.x;
  for (; i < nwords; i += s) p[i] = 0u;
}

__global__ __launch_bounds__(64) void init_ctrl_k(Ctrl* c0, unsigned k0,
                                                  Ctrl* c1, unsigned k1) {
  if (threadIdx.x == 0 && blockIdx.x == 0) {
    c0->prefix = 0u; c0->rank = k0; c0->thr = 0.0f; c0->ovf = 0u;
    c1->prefix = 0u; c1->rank = k1; c1->thr = 0.0f; c1->ovf = 0u;
  }
}

// Locate rank within a histogram of up to 8192 bins. 1024 threads, wave scan.
__global__ __launch_bounds__(1024) void scan_stage_k(
    const unsigned* __restrict__ hist, int bits, Ctrl* __restrict__ ctrl)
{
  __shared__ unsigned wsum[16];
  __shared__ unsigned wbase[16];
  const unsigned nb = 1u << bits;
  const unsigned per = (nb + 1023u) >> 10;
  const unsigned t = threadIdx.x;
  const unsigned lo = t * per;
  const unsigned hi = (lo + per < nb) ? (lo + per) : nb;
  const unsigned oldPrefix = ctrl->prefix;
  const unsigned r = ctrl->rank;
  unsigned s = 0;
  for (unsigned j = lo; j < hi; ++j) s += hist[j];
  const unsigned lane = t & 63u;
  const unsigned wid = t >> 6;
  unsigned run = s;
  for (unsigned o = 1; o < 64; o <<= 1) {
    unsigned v = __shfl_up(run, o, 64);
    if (lane >= o) run += v;
  }
  if (lane == 63u) wsum[wid] = run;
  __syncthreads();
  if (t == 0) {
    unsigned acc = 0;
    for (int i = 0; i < 16; ++i) { wbase[i] = acc; acc += wsum[i]; }
  }
  __syncthreads();
  const unsigned base = wbase[wid] + run - s;   // exclusive prefix for this thread
  if (s > 0 && r >= base && r < base + s) {
    unsigned c = base;
    for (unsigned j = lo; j < hi; ++j) {
      unsigned cnt = hist[j];
      if (r < c + cnt) {
        ctrl->prefix = (oldPrefix << bits) | j;
        ctrl->rank = r - c;
        break;
      }
      c += cnt;
    }
  }
}

__global__ __launch_bounds__(64) void combine_thr_k(Ctrl* a, const Ctrl* b,
                                                    float lw, float hw) {
  if (threadIdx.x == 0 && blockIdx.x == 0) {
    float v0 = __uint_as_float(a->prefix);
    float v1 = __uint_as_float(b->prefix);
    float tq = __fadd_rn(__fmul_rn(v0, lw), __fmul_rn(v1, hw));
    float num = __fmul_rn(tq, 0.1f);
    a->thr = __fdiv_rn(num, 0.1f);
  }
}

// ---------------- fast path ----------------

__global__ __launch_bounds__(256) void setup_compact_k(unsigned* arena, unsigned k0) {
  const unsigned start = 32u;
  const unsigned total = ARENA_WORDS - start;
  const unsigned gstr = gridDim.x * 256u;
  for (unsigned i = blockIdx.x * 256u + threadIdx.x; i < total; i += gstr)
    arena[start + i] = 0u;
  if (blockIdx.x == 0 && threadIdx.x == 0) {
    Ctrl* c = (Ctrl*)arena;
    c->prefix = 0u; c->rank = k0; c->thr = 0.0f; c->ovf = 0u;
  }
}

// 13-bit hist with two bank-shifted LDS copies (lane parity) to cut
// same-bank atomic serialization on the hot bins of normal data.
__global__ __launch_bounds__(512) void hist13_k(
    const uint4* __restrict__ x4, long long n4,
    const unsigned* __restrict__ xs, long long n,
    unsigned* __restrict__ hist)
{
  __shared__ unsigned lh[16392];          // copy0 @0, copy1 @8200 (+8 banks)
  const unsigned off = (threadIdx.x & 1u) ? 8200u : 0u;
  for (unsigned i = threadIdx.x; i < 16392u; i += 512u) lh[i] = 0u;
  __syncthreads();
  const long long stride = (long long)gridDim.x * blockDim.x;
  long long i = (long long)blockIdx.x * blockDim.x + threadIdx.x;
  for (; i + stride < n4; i += 2 * stride) {
    uint4 a = x4[i];
    uint4 b = x4[i + stride];
    atomicAdd(&lh[((a.x & 0x7fffffffu) >> 18) + off], 1u);
    atomicAdd(&lh[((a.y & 0x7fffffffu) >> 18) + off], 1u);
    atomicAdd(&lh[((a.z & 0x7fffffffu) >> 18) + off], 1u);
    atomicAdd(&lh[((a.w & 0x7fffffffu) >> 18) + off], 1u);
    atomicAdd(&lh[((b.x & 0x7fffffffu) >> 18) + off], 1u);
    atomicAdd(&lh[((b.y & 0x7fffffffu) >> 18) + off], 1u);
    atomicAdd(&lh[((b.z & 0x7fffffffu) >> 18) + off], 1u);
    atomicAdd(&lh[((b.w & 0x7fffffffu) >> 18) + off], 1u);
  }
  for (; i < n4; i += stride) {
    uint4 a = x4[i];
    atomicAdd(&lh[((a.x & 0x7fffffffu) >> 18) + off], 1u);
    atomicAdd(&lh[((a.y & 0x7fffffffu) >> 18) + off], 1u);
    atomicAdd(&lh[((a.z & 0x7fffffffu) >> 18) + off], 1u);
    atomicAdd(&lh[((a.w & 0x7fffffffu) >> 18) + off], 1u);
  }
  long long t = n4 * 4 + (long long)blockIdx.x * blockDim.x + threadIdx.x;
  for (; t < n; t += stride)
    atomicAdd(&lh[((xs[t] & 0x7fffffffu) >> 18) + off], 1u);
  __syncthreads();
  for (unsigned j = threadIdx.x; j < 8192u; j += 512u) {
    unsigned s = lh[j] + lh[j + 8200u];
    if (s) atomicAdd(&hist[j], s);
  }
}

// Fused masked-copy + segmented candidate compaction.
// REVERSE iteration: x's tail is Infinity-Cache-resident after hist13.
// Nontemporal stores keep the output stream from evicting that tail.
__global__ __launch_bounds__(256) void pass2_k(
    const uint4* __restrict__ x4, float4* __restrict__ o4, long long n4,
    const unsigned* __restrict__ xs, float* __restrict__ os, long long n,
    Ctrl* __restrict__ ctrl, unsigned* __restrict__ seg_cnt,
    uint2* __restrict__ cand)
{
  __shared__ unsigned lcnt;
  if (threadIdx.x == 0) lcnt = 0u;
  __syncthreads();
  const unsigned B = ctrl->prefix;
  uint2* __restrict__ seg = cand + (size_t)blockIdx.x * SEGCAP;
  uint2* __restrict__ ovf = cand + (size_t)SEGS * SEGCAP;
  const long long stride = (long long)gridDim.x * blockDim.x;
  long long rpos = (long long)blockIdx.x * blockDim.x + threadIdx.x;
  for (; rpos < n4; rpos += stride) {
    const long long i = n4 - 1 - rpos;          // reverse order
    uint4 v = x4[i];
    unsigned bidx = (unsigned)(i * 4);
    fx4 w;
    #pragma unroll
    for (int c = 0; c < 4; ++c) {
      unsigned raw = (&v.x)[c];
      unsigned b = (raw & 0x7fffffffu) >> 18;
      float val = __uint_as_float(raw);
      w[c] = (b > B + 1u) ? val : 0.0f;
      if (b == B || b == B + 1u) {
        unsigned pos = atomicAdd(&lcnt, 1u);
        uint2 e; e.x = raw; e.y = bidx + (unsigned)c;
        if (pos < SEGCAP) seg[pos] = e;
        else {
          unsigned opos = atomicAdd(&ctrl->ovf, 1u);
          if (opos < OCAP) ovf[opos] = e;
        }
      }
    }
    __builtin_nontemporal_store(w, (fx4*)&o4[i]);
  }
  long long t = n4 * 4 + (long long)blockIdx.x * blockDim.x + threadIdx.x;
  for (; t < n; t += stride) {
    unsigned raw = xs[t];
    unsigned b = (raw & 0x7fffffffu) >> 18;
    float val = __uint_as_float(raw);
    os[t] = (b > B + 1u) ? val : 0.0f;
    if (b == B || b == B + 1u) {
      unsigned pos = atomicAdd(&lcnt, 1u);
      uint2 e; e.x = raw; e.y = (unsigned)t;
      if (pos < SEGCAP) seg[pos] = e;
      else {
        unsigned opos = atomicAdd(&ctrl->ovf, 1u);
        if (opos < OCAP) ovf[opos] = e;
      }
    }
  }
  __syncthreads();
  if (threadIdx.x == 0)
    seg_cnt[blockIdx.x] = (lcnt < SEGCAP) ? lcnt : SEGCAP;
}

// Single 18-bit refine: global atomics into 262144 bins (~3 hits/bin).
__global__ __launch_bounds__(256) void cand_hist18_k(
    const uint2* __restrict__ cand, const unsigned* __restrict__ seg_cnt,
    const Ctrl* __restrict__ ctrl, unsigned* __restrict__ h18)
{
  const unsigned prefix = ctrl->prefix;
  const uint2* __restrict__ seg = cand + (size_t)blockIdx.x * SEGCAP;
  unsigned cnt = seg_cnt[blockIdx.x];
  for (unsigned t = threadIdx.x; t < cnt; t += (unsigned)blockDim.x) {
    unsigned key = seg[t].x & 0x7fffffffu;
    if ((key >> 18) == prefix) atomicAdd(&h18[key & 0x3ffffu], 1u);
  }
  if (blockIdx.x == 0) {
    unsigned oc = ctrl->ovf; if (oc > OCAP) oc = OCAP;
    const uint2* __restrict__ ovf = cand + (size_t)SEGS * SEGCAP;
    for (unsigned t = threadIdx.x; t < oc; t += (unsigned)blockDim.x) {
      unsigned key = ovf[t].x & 0x7fffffffu;
      if ((key >> 18) == prefix) atomicAdd(&h18[key & 0x3ffffu], 1u);
    }
  }
}

// Phase 1 of the 18-bit scan: per-1024-bin chunk sums (grid = nchunks blocks).
__global__ __launch_bounds__(256) void scan_big1_k(
    const unsigned* __restrict__ hist, unsigned* __restrict__ chunkSums)
{
  __shared__ unsigned red[256];
  const unsigned base = blockIdx.x * 1024u;
  unsigned s = 0;
  for (unsigned i = threadIdx.x; i < 1024u; i += 256u) s += hist[base + i];
  red[threadIdx.x] = s;
  __syncthreads();
  for (unsigned off = 128; off > 0; off >>= 1) {
    if (threadIdx.x < off) red[threadIdx.x] += red[threadIdx.x + off];
    __syncthreads();
  }
  if (threadIdx.x == 0) chunkSums[blockIdx.x] = red[0];
}

// Phase 2 (fast path, 256 chunks, 18-bit subkey): pick chunk, LDS-scan it.
__global__ __launch_bounds__(1024) void scan18b_k(
    const unsigned* __restrict__ hist, const unsigned* __restrict__ chunkSums,
    Ctrl* __restrict__ ctrl)
{
  __shared__ unsigned cs[256];
  __shared__ unsigned sc[1024];
  __shared__ unsigned sel[2];
  const unsigned t = threadIdx.x;
  const unsigned oldPrefix = ctrl->prefix;
  const unsigned r = ctrl->rank;
  if (t < 256) cs[t] = chunkSums[t];
  __syncthreads();
  if (t == 0) {
    unsigned run = 0, ci = 0, cb = 0;
    for (int i = 0; i < 256; ++i) {
      unsigned cnt = cs[i];
      if (r >= run && r < run + cnt) { ci = (unsigned)i; cb = run; }
      run += cnt;
    }
    sel[0] = ci; sel[1] = cb;
  }
  __syncthreads();
  const unsigned ci = sel[0];
  const unsigned cb = sel[1];
  const unsigned val = hist[ci * 1024u + t];
  sc[t] = val;
  __syncthreads();
  for (unsigned off = 1; off < 1024; off <<= 1) {
    unsigned add = (t >= off) ? sc[t - off] : 0u;
    __syncthreads();
    sc[t] += add;
    __syncthreads();
  }
  const unsigned incl = sc[t];
  const unsigned excl = incl - val;
  const unsigned rr = r - cb;
  if (val > 0 && rr >= excl && rr < incl) {
    ctrl->prefix = (oldPrefix << 18) | (ci * 1024u + t);
    ctrl->rank = rr - excl;
  }
}

// Scatter-fix: write back candidates that survive the exact threshold test.
__global__ __launch_bounds__(256) void fixup_k(
    const uint2* __restrict__ cand, const unsigned* __restrict__ seg_cnt,
    const Ctrl* __restrict__ ctrl, float* __restrict__ out)
{
  const float thr = ctrl->thr;
  const uint2* __restrict__ seg = cand + (size_t)blockIdx.x * SEGCAP;
  unsigned cnt = seg_cnt[blockIdx.x];
  for (unsigned t = threadIdx.x; t < cnt; t += (unsigned)blockDim.x) {
    uint2 e = seg[t];
    float v = __uint_as_float(e.x);
    if (fabsf(v) > thr) out[e.y] = v;
  }
  if (blockIdx.x == 0) {
    unsigned oc = ctrl->ovf; if (oc > OCAP) oc = OCAP;
    const uint2* __restrict__ ovf = cand + (size_t)SEGS * SEGCAP;
    for (unsigned t = threadIdx.x; t < oc; t += (unsigned)blockDim.x) {
      uint2 e = ovf[t];
      float v = __uint_as_float(e.x);
      if (fabsf(v) > thr) out[e.y] = v;
    }
  }
}

// ---------------- fallback path ----------------

__global__ __launch_bounds__(256) void hist_stage_k(
    const uint4* __restrict__ x4, long long n4,
    const unsigned* __restrict__ xs, long long n,
    unsigned* __restrict__ hist,
    const Ctrl* __restrict__ ctrl,
    int shift, int bits)
{
  __shared__ unsigned lh[4096];
  const unsigned nb = 1u << bits;
  const bool lds = (bits <= 12);
  if (lds) {
    for (unsigned i = threadIdx.x; i < nb; i += blockDim.x) lh[i] = 0u;
    __syncthreads();
  }
  const unsigned prefix = ctrl->prefix;
  const int top = shift + bits;
  const unsigned m = nb - 1u;
  const long long stride = (long long)gridDim.x * blockDim.x;
  long long i = (long long)blockIdx.x * blockDim.x + threadIdx.x;
  for (; i < n4; i += stride) {
    uint4 v = x4[i];
    unsigned a = v.x & 0x7fffffffu;
    unsigned b = v.y & 0x7fffffffu;
    unsigned c = v.z & 0x7fffffffu;
    unsigned d = v.w & 0x7fffffffu;
    if (lds) {
      if ((a >> top) == prefix) atomicAdd(&lh[(a >> shift) & m], 1u);
      if ((b >> top) == prefix) atomicAdd(&lh[(b >> shift) & m], 1u);
      if ((c >> top) == prefix) atomicAdd(&lh[(c >> shift) & m], 1u);
      if ((d >> top) == prefix) atomicAdd(&lh[(d >> shift) & m], 1u);
    } else {
      if ((a >> top) == prefix) atomicAdd(&hist[(a >> shift) & m], 1u);
      if ((b >> top) == prefix) atomicAdd(&hist[(b >> shift) & m], 1u);
      if ((c >> top) == prefix) atomicAdd(&hist[(c >> shift) & m], 1u);
      if ((d >> top) == prefix) atomicAdd(&hist[(d >> shift) & m], 1u);
    }
  }
  long long t = n4 * 4 + (long long)blockIdx.x * blockDim.x + threadIdx.x;
  for (; t < n; t += stride) {
    unsigned u = xs[t] & 0x7fffffffu;
    if ((u >> top) == prefix) {
      if (lds) atomicAdd(&lh[(u >> shift) & m], 1u);
      else     atomicAdd(&hist[(u >> shift) & m], 1u);
    }
  }
  if (lds) {
    __syncthreads();
    for (unsigned j = threadIdx.x; j < nb; j += blockDim.x) {
      unsigned cv = lh[j];
      if (cv) atomicAdd(&hist[j], cv);
    }
  }
}

__global__ __launch_bounds__(1024) void scan_big2_k(
    const unsigned* __restrict__ hist, const unsigned* __restrict__ chunkSums,
    Ctrl* __restrict__ ctrl)
{
  __shared__ unsigned cs[512];
  __shared__ unsigned sc[1024];
  __shared__ unsigned sel[2];
  const unsigned t = threadIdx.x;
  const unsigned oldPrefix = ctrl->prefix;
  const unsigned r = ctrl->rank;
  if (t < 512) cs[t] = chunkSums[t];
  __syncthreads();
  if (t == 0) {
    unsigned run = 0, ci = 0, cb = 0;
    for (int i = 0; i < 512; ++i) {
      unsigned cnt = cs[i];
      if (r >= run && r < run + cnt) { ci = (unsigned)i; cb = run; }
      run += cnt;
    }
    sel[0] = ci; sel[1] = cb;
  }
  __syncthreads();
  const unsigned ci = sel[0];
  const unsigned cb = sel[1];
  const unsigned val = hist[ci * 1024u + t];
  sc[t] = val;
  __syncthreads();
  for (unsigned off = 1; off < 1024; off <<= 1) {
    unsigned add = (t >= off) ? sc[t - off] : 0u;
    __syncthreads();
    sc[t] += add;
    __syncthreads();
  }
  const unsigned incl = sc[t];
  const unsigned excl = incl - val;
  const unsigned rr = r - cb;
  if (val > 0 && rr >= excl && rr < incl) {
    ctrl->prefix = (oldPrefix << 19) | (ci * 1024u + t);
    ctrl->rank = rr - excl;
  }
}

__global__ __launch_bounds__(256) void mask_k(
    const float4* __restrict__ x4, float4* __restrict__ o4, long long n4,
    const float* __restrict__ xs, float* __restrict__ os, long long n,
    const Ctrl* __restrict__ ctrl)
{
  const float thr = ctrl->thr;
  const long long stride = (long long)gridDim.x * blockDim.x;
  long long i = (long long)blockIdx.x * blockDim.x + threadIdx.x;
  for (; i < n4; i += stride) {
    float4 v = x4[i];
    float4 w;
    w.x = (fabsf(v.x) <= thr) ? 0.0f : v.x;
    w.y = (fabsf(v.y) <= thr) ? 0.0f : v.y;
    w.z = (fabsf(v.z) <= thr) ? 0.0f : v.z;
    w.w = (fabsf(v.w) <= thr) ? 0.0f : v.w;
    o4[i] = w;
  }
  long long t = n4 * 4 + (long long)blockIdx.x * blockDim.x + threadIdx.x;
  for (; t < n; t += stride) {
    float v = xs[t];
    os[t] = (fabsf(v) <= thr) ? 0.0f : v;
  }
}

// ---------------- launch ----------------

extern "C" void kernel_launch(void* const* d_in, const int* in_sizes, int n_in,
                              void* d_out, int out_size, void* d_ws, size_t ws_size,
                              hipStream_t stream)
{
  const float* x = (const float*)d_in[0];
  const long long N = (long long)in_sizes[0];
  const long long n4 = N >> 2;
  const uint4* x4 = (const uint4*)x;
  const unsigned* xbits = (const unsigned*)x;

  // jnp.quantile fp32 index math: idx = 0.5f * f32(N-1).
  float idxf = 0.5f * (float)(N - 1);
  float lowf = floorf(idxf);
  float highf = ceilf(idxf);
  float hw = idxf - lowf;
  float lw = 1.0f - hw;
  unsigned k0 = (unsigned)lowf;
  unsigned k1 = (unsigned)highf;
  int dual = (hw != 0.0f);
  if (!dual) k1 = k0;

  const size_t needC = CAND_BYTE_OFF + ((size_t)SEGS * SEGCAP + OCAP) * 8;  // ~34.5 MB

  if (!dual && N < (1ll << 32) && ws_size >= needC) {
    unsigned* arena = (unsigned*)d_ws;
    Ctrl* c0 = (Ctrl*)arena;
    unsigned* h1 = arena + W_H1;
    unsigned* seg_cnt = arena + W_SEGCNT;
    unsigned* chunkSums = arena + W_CHUNK;
    unsigned* h18 = arena + W_H18;
    uint2* cand = (uint2*)((char*)d_ws + CAND_BYTE_OFF);

    setup_compact_k<<<128, 256, 0, stream>>>(arena, k0);
    hist13_k<<<1024, 512, 0, stream>>>(x4, n4, xbits, N, h1);
    scan_stage_k<<<1, 1024, 0, stream>>>(h1, 13, c0);
    pass2_k<<<SEGS, 256, 0, stream>>>(x4, (float4*)d_out, n4, xbits, (float*)d_out, N,
                                      c0, seg_cnt, cand);
    cand_hist18_k<<<SEGS, 256, 0, stream>>>(cand, seg_cnt, c0, h18);
    scan_big1_k<<<256, 256, 0, stream>>>(h18, chunkSums);
    scan18b_k<<<1, 1024, 0, stream>>>(h18, chunkSums, c0);
    combine_thr_k<<<1, 64, 0, stream>>>(c0, c0, lw, hw);
    fixup_k<<<SEGS, 256, 0, stream>>>(cand, seg_cnt, c0, (float*)d_out);
    return;
  }

  // ---------- fallback: two-full-hist structure with kernel zeroing ----------
  const size_t needA = 65536 + (size_t)(1u << 19) * 4;  // 2,162,688
  char* wsb = (char*)d_ws;
  char* arena = (ws_size >= needA) ? wsb : (char*)d_out;  // d_out fully rewritten at end
  Ctrl* c0 = (ws_size >= 128) ? (Ctrl*)wsb : (Ctrl*)arena;
  Ctrl* c1 = c0 + 1;
  unsigned* chunkSums = (unsigned*)(arena + 128);
  unsigned* h1 = (unsigned*)(arena + 4096);
  unsigned* h2 = (unsigned*)(arena + 65536);
  const long long zwords = (long long)(needA - 4096) / 4;

  zero_words_k<<<512, 256, 0, stream>>>((unsigned*)(arena + 4096), zwords);
  init_ctrl_k<<<1, 64, 0, stream>>>(c0, k0, (dual ? c1 : c0), k1);

  const int nchain = dual ? 2 : 1;
  for (int chain = 0; chain < nchain; ++chain) {
    Ctrl* cc = chain ? c1 : c0;
    if (chain) zero_words_k<<<512, 256, 0, stream>>>((unsigned*)(arena + 4096), zwords);
    hist_stage_k<<<2048, 256, 0, stream>>>(x4, n4, xbits, N, h1, cc, 19, 12);
    scan_stage_k<<<1, 1024, 0, stream>>>(h1, 12, cc);
    hist_stage_k<<<2048, 256, 0, stream>>>(x4, n4, xbits, N, h2, cc, 0, 19);
    scan_big1_k<<<512, 256, 0, stream>>>(h2, chunkSums);
    scan_big2_k<<<1, 1024, 0, stream>>>(h2, chunkSums, cc);
  }
  combine_thr_k<<<1, 64, 0, stream>>>(c0, (dual ? c1 : c0), lw, hw);
  mask_k<<<2048, 256, 0, stream>>>((const float4*)x, (float4*)d_out, n4,
                                   x, (float*)d_out, N, c0);
}

// Round 6
// 269.267 us; speedup vs baseline: 43.5532x; 1.2476x over previous
//
#include <hip/hip_runtime.h>
#include <stdint.h>

// Exact global median-of-|x| + masked copy, one full-data pass.
// thr replicates jnp fp32 semantics: thr = (t*0.1f)/0.1f (RN).
//
// Fast path (ws >= ~38MB):
//   S1: sampled 13-bit hist (16MB read) -> candidate key range [Klo,Khi)
//       (12-sigma margin + 4-ulp boundary patches)
//   S2: MEGA pass (read 360MB + nt-write 375MB): classify by 2 key compares,
//       count below, segment-compact candidates (~2.7M, L2-resident)
//   S3: exact select over candidates: 13-bit hist -> B,rank; 18-bit refine
//       -> exact key -> thr; scatter-fix survivors
//   S4: unconditional exactness: verified invariants else gated repair chain
//       (5 early-exit kernels) recomputes select+mask from full data.
// Fallback (small ws / interpolated quantile): two-full-hist radix select.

struct Ctrl {
  unsigned prefix;   // selected bin / final key
  unsigned rank;     // remaining rank
  float    thr;      // final threshold
  unsigned ovf;      // overflow candidate count
  unsigned below;    // exact count of keys < Klo
  unsigned blo;      // sample-interval low bin  (atomicMax)
  unsigned bhi;      // sample-interval high bin (atomicMin)
  unsigned flag;     // repair needed
};

typedef float fx4 __attribute__((ext_vector_type(4)));

#define SEGS   1024u
#define SEGCAP 4096u
#define OCAP   131072u

// Arena word offsets (zeroed each call by setup_k):
#define W_HS     32u        // sample hist   (8192)
#define W_H13C   8224u      // cand 13-bit   (8192)
#define W_H13R   16416u     // repair 13-bit (8192)
#define W_SEGCNT 24608u     // seg_cnt       (1024)
#define W_CHUNK  25632u     // chunkSums     (256)
#define W_H18    32768u     // cand 18-bit   (262144)
#define W_H18R   294912u    // repair 18-bit (262144)
#define ARENA_WORDS 557056u
#define CAND_BYTE_OFF 4194304u

// ---------------- small shared kernels ----------------

__global__ __launch_bounds__(256) void zero_words_k(unsigned* __restrict__ p, long long nwords) {
  long long i = (long long)blockIdx.x * blockDim.x + threadIdx.x;
  long long s = (long long)gridDim.x * blockDim.x;
  for (; i < nwords; i += s) p[i] = 0u;
}

__global__ __launch_bounds__(64) void init_ctrl_k(Ctrl* c0, unsigned k0,
                                                  Ctrl* c1, unsigned k1) {
  if (threadIdx.x == 0 && blockIdx.x == 0) {
    c0->prefix = 0u; c0->rank = k0; c0->thr = 0.0f; c0->ovf = 0u;
    c1->prefix = 0u; c1->rank = k1; c1->thr = 0.0f; c1->ovf = 0u;
  }
}

__global__ __launch_bounds__(64) void combine_thr_k(Ctrl* a, const Ctrl* b,
                                                    float lw, float hw) {
  if (threadIdx.x == 0 && blockIdx.x == 0) {
    float v0 = __uint_as_float(a->prefix);
    float v1 = __uint_as_float(b->prefix);
    float tq = __fadd_rn(__fmul_rn(v0, lw), __fmul_rn(v1, hw));
    a->thr = __fdiv_rn(__fmul_rn(tq, 0.1f), 0.1f);
  }
}

// ---------------- fast path ----------------

__global__ __launch_bounds__(256) void setup_k(unsigned* arena, unsigned k0) {
  const unsigned gstr = gridDim.x * 256u;
  for (unsigned i = blockIdx.x * 256u + threadIdx.x; i < ARENA_WORDS; i += gstr)
    arena[i] = 0u;
  if (blockIdx.x == 0) {
    __syncthreads();
    if (threadIdx.x == 0) {
      Ctrl* c = (Ctrl*)arena;
      c->rank = k0;
      c->bhi = 8191u;      // atomicMin target
    }
  }
}

// S1a: sampled 13-bit hist. 4096 chunks x 256 float4 (16MB, 4.19M samples).
__global__ __launch_bounds__(256) void sample13_k(
    const uint4* __restrict__ x4, long long n4, unsigned* __restrict__ hs)
{
  __shared__ unsigned lh[8192];
  for (unsigned i = threadIdx.x; i < 8192u; i += 256u) lh[i] = 0u;
  __syncthreads();
  const long long cstride = n4 >> 12;          // n4 / 4096 chunks
  for (unsigned j = 0; j < 16u; ++j) {
    unsigned c = blockIdx.x * 16u + j;
    long long idx = (long long)c * cstride + threadIdx.x;
    if (idx < n4) {
      uint4 v = x4[idx];
      atomicAdd(&lh[(v.x & 0x7fffffffu) >> 18], 1u);
      atomicAdd(&lh[(v.y & 0x7fffffffu) >> 18], 1u);
      atomicAdd(&lh[(v.z & 0x7fffffffu) >> 18], 1u);
      atomicAdd(&lh[(v.w & 0x7fffffffu) >> 18], 1u);
    }
  }
  __syncthreads();
  for (unsigned j = threadIdx.x; j < 8192u; j += 256u) {
    unsigned s = lh[j];
    if (s) atomicAdd(&hs[j], s);
  }
}

// S1b: interval [blo,bhi] from sample hist with count margin [tlo,thi].
__global__ __launch_bounds__(1024) void sscan_k(
    const unsigned* __restrict__ h, Ctrl* __restrict__ ctrl,
    unsigned tlo, unsigned thi)
{
  __shared__ unsigned wsum[16], wbase[16];
  const unsigned t = threadIdx.x, lane = t & 63u, wid = t >> 6;
  const unsigned lo = t * 8u, hi = lo + 8u;
  unsigned s = 0;
  for (unsigned j = lo; j < hi; ++j) s += h[j];
  unsigned run = s;
  for (unsigned o = 1; o < 64; o <<= 1) {
    unsigned v = __shfl_up(run, o, 64);
    if (lane >= o) run += v;
  }
  if (lane == 63u) wsum[wid] = run;
  __syncthreads();
  if (t == 0) { unsigned acc = 0; for (int i = 0; i < 16; ++i) { wbase[i] = acc; acc += wsum[i]; } }
  __syncthreads();
  unsigned c = wbase[wid] + run - s;     // exclusive prefix at bin lo
  int myblo = -1;
  int mybhi = -1;
  for (unsigned j = lo; j < hi; ++j) {
    unsigned excl = c;
    c += h[j];
    if (excl < tlo) myblo = (int)j;
    if (mybhi < 0 && c > thi) mybhi = (int)j;
  }
  if (myblo >= 0) atomicMax(&ctrl->blo, (unsigned)myblo);
  if (mybhi >= 0) atomicMin(&ctrl->bhi, (unsigned)mybhi);
}

// S2: the single full pass. Classify, count below, compact candidates.
__global__ __launch_bounds__(512) void mega_k(
    const uint4* __restrict__ x4, float4* __restrict__ o4, long long n4,
    const unsigned* __restrict__ xs, float* __restrict__ os, long long n,
    Ctrl* __restrict__ ctrl, unsigned* __restrict__ seg_cnt,
    uint2* __restrict__ cand)
{
  __shared__ unsigned lcnt;
  __shared__ unsigned wred[8];
  if (threadIdx.x == 0) lcnt = 0u;
  __syncthreads();
  const unsigned blo = ctrl->blo, bhi = ctrl->bhi;
  unsigned Klo = blo << 18;
  Klo = (Klo >= 4u) ? Klo - 4u : 0u;
  unsigned Khi;
  if (bhi >= 8191u) Khi = 0x7fffffffu;
  else {
    unsigned e = (bhi + 1u) << 18;
    Khi = (e <= 0x7ffffffbu) ? e + 4u : 0x7fffffffu;
  }
  uint2* __restrict__ seg = cand + (size_t)blockIdx.x * SEGCAP;
  uint2* __restrict__ ovf = cand + (size_t)SEGS * SEGCAP;
  unsigned below = 0;
  const long long stride = (long long)gridDim.x * blockDim.x;
  for (long long i = (long long)blockIdx.x * blockDim.x + threadIdx.x; i < n4; i += stride) {
    uint4 v = x4[i];
    unsigned bidx = (unsigned)(i * 4);
    fx4 w;
    #pragma unroll
    for (int c = 0; c < 4; ++c) {
      unsigned raw = (&v.x)[c];
      unsigned key = raw & 0x7fffffffu;
      float val = __uint_as_float(raw);
      bool keep = key >= Khi;
      w[c] = keep ? val : 0.0f;
      if (key < Klo) below++;
      else if (!keep) {
        unsigned pos = atomicAdd(&lcnt, 1u);
        uint2 e; e.x = raw; e.y = bidx + (unsigned)c;
        if (pos < SEGCAP) seg[pos] = e;
        else { unsigned op = atomicAdd(&ctrl->ovf, 1u); if (op < OCAP) ovf[op] = e; }
      }
    }
    __builtin_nontemporal_store(w, (fx4*)&o4[i]);
  }
  for (long long t = n4 * 4 + (long long)blockIdx.x * blockDim.x + threadIdx.x; t < n; t += stride) {
    unsigned raw = xs[t];
    unsigned key = raw & 0x7fffffffu;
    float val = __uint_as_float(raw);
    bool keep = key >= Khi;
    os[t] = keep ? val : 0.0f;
    if (key < Klo) below++;
    else if (!keep) {
      unsigned pos = atomicAdd(&lcnt, 1u);
      uint2 e; e.x = raw; e.y = (unsigned)t;
      if (pos < SEGCAP) seg[pos] = e;
      else { unsigned op = atomicAdd(&ctrl->ovf, 1u); if (op < OCAP) ovf[op] = e; }
    }
  }
  for (int o = 32; o > 0; o >>= 1) below += __shfl_down(below, o, 64);
  if ((threadIdx.x & 63u) == 0u) wred[threadIdx.x >> 6] = below;
  __syncthreads();
  if (threadIdx.x == 0) {
    unsigned s = 0;
    for (int i = 0; i < 8; ++i) s += wred[i];
    atomicAdd(&ctrl->below, s);
    seg_cnt[blockIdx.x] = (lcnt < SEGCAP) ? lcnt : SEGCAP;
  }
}

// S3a: 13-bit hist over compacted candidates.
__global__ __launch_bounds__(256) void cand13_k(
    const uint2* __restrict__ cand, const unsigned* __restrict__ seg_cnt,
    const Ctrl* __restrict__ ctrl, unsigned* __restrict__ h13c)
{
  __shared__ unsigned lh[8192];
  for (unsigned i = threadIdx.x; i < 8192u; i += 256u) lh[i] = 0u;
  __syncthreads();
  const uint2* __restrict__ seg = cand + (size_t)blockIdx.x * SEGCAP;
  unsigned cnt = seg_cnt[blockIdx.x];
  for (unsigned t = threadIdx.x; t < cnt; t += 256u)
    atomicAdd(&lh[(seg[t].x & 0x7fffffffu) >> 18], 1u);
  if (blockIdx.x == 0) {
    unsigned oc = ctrl->ovf; if (oc > OCAP) oc = OCAP;
    const uint2* __restrict__ ovf = cand + (size_t)SEGS * SEGCAP;
    for (unsigned t = threadIdx.x; t < oc; t += 256u)
      atomicAdd(&lh[(ovf[t].x & 0x7fffffffu) >> 18], 1u);
  }
  __syncthreads();
  for (unsigned j = threadIdx.x; j < 8192u; j += 256u) {
    unsigned s = lh[j];
    if (s) atomicAdd(&h13c[j], s);
  }
}

// S3b: exact B + rank from candidate hist; verify invariants -> flag.
__global__ __launch_bounds__(1024) void scan13c_k(
    const unsigned* __restrict__ h, Ctrl* __restrict__ ctrl, unsigned k0)
{
  __shared__ unsigned wsum[16], wbase[16];
  __shared__ unsigned sh_total;
  const unsigned t = threadIdx.x, lane = t & 63u, wid = t >> 6;
  const unsigned lo = t * 8u, hi = lo + 8u;
  unsigned s = 0;
  for (unsigned j = lo; j < hi; ++j) s += h[j];
  unsigned run = s;
  for (unsigned o = 1; o < 64; o <<= 1) {
    unsigned v = __shfl_up(run, o, 64);
    if (lane >= o) run += v;
  }
  if (lane == 63u) wsum[wid] = run;
  __syncthreads();
  if (t == 0) {
    unsigned acc = 0;
    for (int i = 0; i < 16; ++i) { wbase[i] = acc; acc += wsum[i]; }
    sh_total = acc;
  }
  __syncthreads();
  const unsigned base = wbase[wid] + run - s;
  const unsigned below = ctrl->below;
  const unsigned ovf = ctrl->ovf;
  const unsigned total = sh_total;
  const unsigned rc = k0 - below;
  const bool bad = (k0 < below) || (rc >= total) || (ovf > OCAP);
  if (t == 0 && bad) atomicOr(&ctrl->flag, 1u);
  if (!bad && s > 0 && rc >= base && rc < base + s) {
    unsigned c = base;
    for (unsigned j = lo; j < hi; ++j) {
      unsigned cnt = h[j];
      if (rc < c + cnt) {
        ctrl->prefix = j;
        ctrl->rank = rc - c;
        if (j < ctrl->blo || j > ctrl->bhi) atomicOr(&ctrl->flag, 1u);
        break;
      }
      c += cnt;
    }
  }
}

// S3c: 18-bit refine over candidates in bin B (global atomics, ~3 hits/bin).
__global__ __launch_bounds__(256) void cand18_k(
    const uint2* __restrict__ cand, const unsigned* __restrict__ seg_cnt,
    const Ctrl* __restrict__ ctrl, unsigned* __restrict__ h18)
{
  const unsigned prefix = ctrl->prefix;
  const uint2* __restrict__ seg = cand + (size_t)blockIdx.x * SEGCAP;
  unsigned cnt = seg_cnt[blockIdx.x];
  for (unsigned t = threadIdx.x; t < cnt; t += 256u) {
    unsigned key = seg[t].x & 0x7fffffffu;
    if ((key >> 18) == prefix) atomicAdd(&h18[key & 0x3ffffu], 1u);
  }
  if (blockIdx.x == 0) {
    unsigned oc = ctrl->ovf; if (oc > OCAP) oc = OCAP;
    const uint2* __restrict__ ovf = cand + (size_t)SEGS * SEGCAP;
    for (unsigned t = threadIdx.x; t < oc; t += 256u) {
      unsigned key = ovf[t].x & 0x7fffffffu;
      if ((key >> 18) == prefix) atomicAdd(&h18[key & 0x3ffffu], 1u);
    }
  }
}

// chunk sums for an 18-bit hist (grid = nbins/1024 blocks).
__global__ __launch_bounds__(256) void scan_big1_k(
    const unsigned* __restrict__ hist, unsigned* __restrict__ chunkSums)
{
  __shared__ unsigned red[256];
  const unsigned base = blockIdx.x * 1024u;
  unsigned s = 0;
  for (unsigned i = threadIdx.x; i < 1024u; i += 256u) s += hist[base + i];
  red[threadIdx.x] = s;
  __syncthreads();
  for (unsigned off = 128; off > 0; off >>= 1) {
    if (threadIdx.x < off) red[threadIdx.x] += red[threadIdx.x + off];
    __syncthreads();
  }
  if (threadIdx.x == 0) chunkSums[blockIdx.x] = red[0];
}

// S3d: select in 18-bit hist (256 chunks) + compute thr.
__global__ __launch_bounds__(1024) void scan18t_k(
    const unsigned* __restrict__ h18, const unsigned* __restrict__ cs,
    Ctrl* __restrict__ ctrl)
{
  __shared__ unsigned csh[256];
  __shared__ unsigned sc[1024];
  __shared__ unsigned sel[2];
  const unsigned t = threadIdx.x;
  const unsigned oldP = ctrl->prefix;
  const unsigned r = ctrl->rank;
  if (t < 256) csh[t] = cs[t];
  __syncthreads();
  if (t == 0) {
    unsigned run = 0, ci = 0, cb = 0;
    for (int i = 0; i < 256; ++i) {
      unsigned cnt = csh[i];
      if (r >= run && r < run + cnt) { ci = (unsigned)i; cb = run; }
      run += cnt;
    }
    sel[0] = ci; sel[1] = cb;
  }
  __syncthreads();
  const unsigned ci = sel[0], cb = sel[1];
  const unsigned val = h18[ci * 1024u + t];
  sc[t] = val;
  __syncthreads();
  for (unsigned off = 1; off < 1024; off <<= 1) {
    unsigned add = (t >= off) ? sc[t - off] : 0u;
    __syncthreads();
    sc[t] += add;
    __syncthreads();
  }
  const unsigned incl = sc[t];
  const unsigned excl = incl - val;
  const unsigned rr = r - cb;
  if (val > 0 && rr >= excl && rr < incl) {
    unsigned key = (oldP << 18) | (ci * 1024u + t);
    float v = __uint_as_float(key);
    ctrl->thr = __fdiv_rn(__fmul_rn(v, 0.1f), 0.1f);
    ctrl->prefix = key;
  }
}

// S3e: scatter-fix surviving candidates.
__global__ __launch_bounds__(256) void fixup_k(
    const uint2* __restrict__ cand, const unsigned* __restrict__ seg_cnt,
    const Ctrl* __restrict__ ctrl, float* __restrict__ out)
{
  const float thr = ctrl->thr;
  const uint2* __restrict__ seg = cand + (size_t)blockIdx.x * SEGCAP;
  unsigned cnt = seg_cnt[blockIdx.x];
  for (unsigned t = threadIdx.x; t < cnt; t += 256u) {
    uint2 e = seg[t];
    float v = __uint_as_float(e.x);
    if (fabsf(v) > thr) out[e.y] = v;
  }
  if (blockIdx.x == 0) {
    unsigned oc = ctrl->ovf; if (oc > OCAP) oc = OCAP;
    const uint2* __restrict__ ovf = cand + (size_t)SEGS * SEGCAP;
    for (unsigned t = threadIdx.x; t < oc; t += 256u) {
      uint2 e = ovf[t];
      float v = __uint_as_float(e.x);
      if (fabsf(v) > thr) out[e.y] = v;
    }
  }
}

// ---------------- gated repair chain (exactness guarantee) ----------------

__global__ __launch_bounds__(256) void r13_k(
    const uint4* __restrict__ x4, long long n4,
    const unsigned* __restrict__ xs, long long n,
    unsigned* __restrict__ h13r, const Ctrl* __restrict__ ctrl)
{
  if (*(volatile const unsigned*)&ctrl->flag == 0u) return;
  __shared__ unsigned lh[8192];
  for (unsigned i = threadIdx.x; i < 8192u; i += 256u) lh[i] = 0u;
  __syncthreads();
  const long long stride = (long long)gridDim.x * blockDim.x;
  for (long long i = (long long)blockIdx.x * blockDim.x + threadIdx.x; i < n4; i += stride) {
    uint4 v = x4[i];
    atomicAdd(&lh[(v.x & 0x7fffffffu) >> 18], 1u);
    atomicAdd(&lh[(v.y & 0x7fffffffu) >> 18], 1u);
    atomicAdd(&lh[(v.z & 0x7fffffffu) >> 18], 1u);
    atomicAdd(&lh[(v.w & 0x7fffffffu) >> 18], 1u);
  }
  for (long long t = n4 * 4 + (long long)blockIdx.x * blockDim.x + threadIdx.x; t < n; t += stride)
    atomicAdd(&lh[(xs[t] & 0x7fffffffu) >> 18], 1u);
  __syncthreads();
  for (unsigned j = threadIdx.x; j < 8192u; j += 256u) {
    unsigned s = lh[j];
    if (s) atomicAdd(&h13r[j], s);
  }
}

__global__ __launch_bounds__(1024) void rscan13_k(
    const unsigned* __restrict__ h, Ctrl* __restrict__ ctrl, unsigned k0)
{
  if (*(volatile const unsigned*)&ctrl->flag == 0u) return;
  __shared__ unsigned wsum[16], wbase[16];
  const unsigned t = threadIdx.x, lane = t & 63u, wid = t >> 6;
  const unsigned lo = t * 8u, hi = lo + 8u;
  unsigned s = 0;
  for (unsigned j = lo; j < hi; ++j) s += h[j];
  unsigned run = s;
  for (unsigned o = 1; o < 64; o <<= 1) {
    unsigned v = __shfl_up(run, o, 64);
    if (lane >= o) run += v;
  }
  if (lane == 63u) wsum[wid] = run;
  __syncthreads();
  if (t == 0) { unsigned acc = 0; for (int i = 0; i < 16; ++i) { wbase[i] = acc; acc += wsum[i]; } }
  __syncthreads();
  const unsigned base = wbase[wid] + run - s;
  if (s > 0 && k0 >= base && k0 < base + s) {
    unsigned c = base;
    for (unsigned j = lo; j < hi; ++j) {
      unsigned cnt = h[j];
      if (k0 < c + cnt) { ctrl->prefix = j; ctrl->rank = k0 - c; break; }
      c += cnt;
    }
  }
}

__global__ __launch_bounds__(256) void rh18_k(
    const uint4* __restrict__ x4, long long n4,
    const unsigned* __restrict__ xs, long long n,
    unsigned* __restrict__ h18r, const Ctrl* __restrict__ ctrl)
{
  if (*(volatile const unsigned*)&ctrl->flag == 0u) return;
  const unsigned prefix = ctrl->prefix;
  const long long stride = (long long)gridDim.x * blockDim.x;
  for (long long i = (long long)blockIdx.x * blockDim.x + threadIdx.x; i < n4; i += stride) {
    uint4 v = x4[i];
    unsigned a = v.x & 0x7fffffffu, b = v.y & 0x7fffffffu;
    unsigned c = v.z & 0x7fffffffu, d = v.w & 0x7fffffffu;
    if ((a >> 18) == prefix) atomicAdd(&h18r[a & 0x3ffffu], 1u);
    if ((b >> 18) == prefix) atomicAdd(&h18r[b & 0x3ffffu], 1u);
    if ((c >> 18) == prefix) atomicAdd(&h18r[c & 0x3ffffu], 1u);
    if ((d >> 18) == prefix) atomicAdd(&h18r[d & 0x3ffffu], 1u);
  }
  for (long long t = n4 * 4 + (long long)blockIdx.x * blockDim.x + threadIdx.x; t < n; t += stride) {
    unsigned u = xs[t] & 0x7fffffffu;
    if ((u >> 18) == prefix) atomicAdd(&h18r[u & 0x3ffffu], 1u);
  }
}

__global__ __launch_bounds__(1024) void rs18_k(
    const unsigned* __restrict__ h, Ctrl* __restrict__ ctrl)
{
  if (*(volatile const unsigned*)&ctrl->flag == 0u) return;
  __shared__ unsigned wsum[16], wbase[16];
  const unsigned t = threadIdx.x, lane = t & 63u, wid = t >> 6;
  const unsigned lo = t * 256u, hi = lo + 256u;
  const unsigned oldP = ctrl->prefix;
  const unsigned r = ctrl->rank;
  unsigned s = 0;
  for (unsigned j = lo; j < hi; ++j) s += h[j];
  unsigned run = s;
  for (unsigned o = 1; o < 64; o <<= 1) {
    unsigned v = __shfl_up(run, o, 64);
    if (lane >= o) run += v;
  }
  if (lane == 63u) wsum[wid] = run;
  __syncthreads();
  if (t == 0) { unsigned acc = 0; for (int i = 0; i < 16; ++i) { wbase[i] = acc; acc += wsum[i]; } }
  __syncthreads();
  const unsigned base = wbase[wid] + run - s;
  if (s > 0 && r >= base && r < base + s) {
    unsigned c = base;
    for (unsigned j = lo; j < hi; ++j) {
      unsigned cnt = h[j];
      if (r < c + cnt) {
        unsigned key = (oldP << 18) | j;
        float v = __uint_as_float(key);
        ctrl->thr = __fdiv_rn(__fmul_rn(v, 0.1f), 0.1f);
        ctrl->prefix = key;
        break;
      }
      c += cnt;
    }
  }
}

__global__ __launch_bounds__(256) void rmask_k(
    const float4* __restrict__ x4, float4* __restrict__ o4, long long n4,
    const float* __restrict__ xs, float* __restrict__ os, long long n,
    const Ctrl* __restrict__ ctrl)
{
  if (*(volatile const unsigned*)&ctrl->flag == 0u) return;
  const float thr = ctrl->thr;
  const long long stride = (long long)gridDim.x * blockDim.x;
  for (long long i = (long long)blockIdx.x * blockDim.x + threadIdx.x; i < n4; i += stride) {
    float4 v = x4[i];
    fx4 w;
    w[0] = (fabsf(v.x) <= thr) ? 0.0f : v.x;
    w[1] = (fabsf(v.y) <= thr) ? 0.0f : v.y;
    w[2] = (fabsf(v.z) <= thr) ? 0.0f : v.z;
    w[3] = (fabsf(v.w) <= thr) ? 0.0f : v.w;
    __builtin_nontemporal_store(w, (fx4*)&o4[i]);
  }
  for (long long t = n4 * 4 + (long long)blockIdx.x * blockDim.x + threadIdx.x; t < n; t += stride) {
    float v = xs[t];
    os[t] = (fabsf(v) <= thr) ? 0.0f : v;
  }
}

// ---------------- fallback path (round-5 structure) ----------------

__global__ __launch_bounds__(1024) void scan_stage_k(
    const unsigned* __restrict__ hist, int bits, Ctrl* __restrict__ ctrl)
{
  __shared__ unsigned wsum[16], wbase[16];
  const unsigned nb = 1u << bits;
  const unsigned per = (nb + 1023u) >> 10;
  const unsigned t = threadIdx.x, lane = t & 63u, wid = t >> 6;
  const unsigned lo = t * per;
  const unsigned hi = (lo + per < nb) ? (lo + per) : nb;
  const unsigned oldPrefix = ctrl->prefix;
  const unsigned r = ctrl->rank;
  unsigned s = 0;
  for (unsigned j = lo; j < hi; ++j) s += hist[j];
  unsigned run = s;
  for (unsigned o = 1; o < 64; o <<= 1) {
    unsigned v = __shfl_up(run, o, 64);
    if (lane >= o) run += v;
  }
  if (lane == 63u) wsum[wid] = run;
  __syncthreads();
  if (t == 0) { unsigned acc = 0; for (int i = 0; i < 16; ++i) { wbase[i] = acc; acc += wsum[i]; } }
  __syncthreads();
  const unsigned base = wbase[wid] + run - s;
  if (s > 0 && r >= base && r < base + s) {
    unsigned c = base;
    for (unsigned j = lo; j < hi; ++j) {
      unsigned cnt = hist[j];
      if (r < c + cnt) {
        ctrl->prefix = (oldPrefix << bits) | j;
        ctrl->rank = r - c;
        break;
      }
      c += cnt;
    }
  }
}

__global__ __launch_bounds__(256) void hist_stage_k(
    const uint4* __restrict__ x4, long long n4,
    const unsigned* __restrict__ xs, long long n,
    unsigned* __restrict__ hist,
    const Ctrl* __restrict__ ctrl,
    int shift, int bits)
{
  __shared__ unsigned lh[4096];
  const unsigned nb = 1u << bits;
  const bool lds = (bits <= 12);
  if (lds) {
    for (unsigned i = threadIdx.x; i < nb; i += blockDim.x) lh[i] = 0u;
    __syncthreads();
  }
  const unsigned prefix = ctrl->prefix;
  const int top = shift + bits;
  const unsigned m = nb - 1u;
  const long long stride = (long long)gridDim.x * blockDim.x;
  long long i = (long long)blockIdx.x * blockDim.x + threadIdx.x;
  for (; i < n4; i += stride) {
    uint4 v = x4[i];
    unsigned a = v.x & 0x7fffffffu;
    unsigned b = v.y & 0x7fffffffu;
    unsigned c = v.z & 0x7fffffffu;
    unsigned d = v.w & 0x7fffffffu;
    if (lds) {
      if ((a >> top) == prefix) atomicAdd(&lh[(a >> shift) & m], 1u);
      if ((b >> top) == prefix) atomicAdd(&lh[(b >> shift) & m], 1u);
      if ((c >> top) == prefix) atomicAdd(&lh[(c >> shift) & m], 1u);
      if ((d >> top) == prefix) atomicAdd(&lh[(d >> shift) & m], 1u);
    } else {
      if ((a >> top) == prefix) atomicAdd(&hist[(a >> shift) & m], 1u);
      if ((b >> top) == prefix) atomicAdd(&hist[(b >> shift) & m], 1u);
      if ((c >> top) == prefix) atomicAdd(&hist[(c >> shift) & m], 1u);
      if ((d >> top) == prefix) atomicAdd(&hist[(d >> shift) & m], 1u);
    }
  }
  long long t = n4 * 4 + (long long)blockIdx.x * blockDim.x + threadIdx.x;
  for (; t < n; t += stride) {
    unsigned u = xs[t] & 0x7fffffffu;
    if ((u >> top) == prefix) {
      if (lds) atomicAdd(&lh[(u >> shift) & m], 1u);
      else     atomicAdd(&hist[(u >> shift) & m], 1u);
    }
  }
  if (lds) {
    __syncthreads();
    for (unsigned j = threadIdx.x; j < nb; j += blockDim.x) {
      unsigned cv = lh[j];
      if (cv) atomicAdd(&hist[j], cv);
    }
  }
}

__global__ __launch_bounds__(1024) void scan_big2_k(
    const unsigned* __restrict__ hist, const unsigned* __restrict__ chunkSums,
    Ctrl* __restrict__ ctrl)
{
  __shared__ unsigned cs[512];
  __shared__ unsigned sc[1024];
  __shared__ unsigned sel[2];
  const unsigned t = threadIdx.x;
  const unsigned oldPrefix = ctrl->prefix;
  const unsigned r = ctrl->rank;
  if (t < 512) cs[t] = chunkSums[t];
  __syncthreads();
  if (t == 0) {
    unsigned run = 0, ci = 0, cb = 0;
    for (int i = 0; i < 512; ++i) {
      unsigned cnt = cs[i];
      if (r >= run && r < run + cnt) { ci = (unsigned)i; cb = run; }
      run += cnt;
    }
    sel[0] = ci; sel[1] = cb;
  }
  __syncthreads();
  const unsigned ci = sel[0], cb = sel[1];
  const unsigned val = hist[ci * 1024u + t];
  sc[t] = val;
  __syncthreads();
  for (unsigned off = 1; off < 1024; off <<= 1) {
    unsigned add = (t >= off) ? sc[t - off] : 0u;
    __syncthreads();
    sc[t] += add;
    __syncthreads();
  }
  const unsigned incl = sc[t];
  const unsigned excl = incl - val;
  const unsigned rr = r - cb;
  if (val > 0 && rr >= excl && rr < incl) {
    ctrl->prefix = (oldPrefix << 19) | (ci * 1024u + t);
    ctrl->rank = rr - excl;
  }
}

__global__ __launch_bounds__(256) void mask_k(
    const float4* __restrict__ x4, float4* __restrict__ o4, long long n4,
    const float* __restrict__ xs, float* __restrict__ os, long long n,
    const Ctrl* __restrict__ ctrl)
{
  const float thr = ctrl->thr;
  const long long stride = (long long)gridDim.x * blockDim.x;
  long long i = (long long)blockIdx.x * blockDim.x + threadIdx.x;
  for (; i < n4; i += stride) {
    float4 v = x4[i];
    float4 w;
    w.x = (fabsf(v.x) <= thr) ? 0.0f : v.x;
    w.y = (fabsf(v.y) <= thr) ? 0.0f : v.y;
    w.z = (fabsf(v.z) <= thr) ? 0.0f : v.z;
    w.w = (fabsf(v.w) <= thr) ? 0.0f : v.w;
    o4[i] = w;
  }
  long long t = n4 * 4 + (long long)blockIdx.x * blockDim.x + threadIdx.x;
  for (; t < n; t += stride) {
    float v = xs[t];
    os[t] = (fabsf(v) <= thr) ? 0.0f : v;
  }
}

// ---------------- launch ----------------

extern "C" void kernel_launch(void* const* d_in, const int* in_sizes, int n_in,
                              void* d_out, int out_size, void* d_ws, size_t ws_size,
                              hipStream_t stream)
{
  const float* x = (const float*)d_in[0];
  const long long N = (long long)in_sizes[0];
  const long long n4 = N >> 2;
  const uint4* x4 = (const uint4*)x;
  const unsigned* xbits = (const unsigned*)x;

  // jnp.quantile fp32 index math: idx = 0.5f * f32(N-1).
  float idxf = 0.5f * (float)(N - 1);
  float lowf = floorf(idxf);
  float highf = ceilf(idxf);
  float hw = idxf - lowf;
  float lw = 1.0f - hw;
  unsigned k0 = (unsigned)lowf;
  unsigned k1 = (unsigned)highf;
  int dual = (hw != 0.0f);
  if (!dual) k1 = k0;

  const size_t needC = CAND_BYTE_OFF + ((size_t)SEGS * SEGCAP + OCAP) * 8;  // ~37 MB

  if (!dual && N < (1ll << 32) && n4 >= 4096 && ws_size >= needC) {
    unsigned* arena = (unsigned*)d_ws;
    Ctrl* c0 = (Ctrl*)arena;
    unsigned* hs        = arena + W_HS;
    unsigned* h13c      = arena + W_H13C;
    unsigned* h13r      = arena + W_H13R;
    unsigned* seg_cnt   = arena + W_SEGCNT;
    unsigned* chunkSums = arena + W_CHUNK;
    unsigned* h18       = arena + W_H18;
    unsigned* h18r      = arena + W_H18R;
    uint2* cand = (uint2*)((char*)d_ws + CAND_BYTE_OFF);

    // sample-count target & 12-sigma margin (ns = 4096*256*4)
    const unsigned long long ns = 4194304ull;
    unsigned target = (unsigned)(((unsigned long long)k0 * ns) / (unsigned long long)N);
    const unsigned m = 12u * 1024u + 32u;
    unsigned tlo = (target > m) ? target - m : 0u;
    unsigned thi = target + m;

    setup_k<<<512, 256, 0, stream>>>(arena, k0);
    sample13_k<<<256, 256, 0, stream>>>(x4, n4, hs);
    sscan_k<<<1, 1024, 0, stream>>>(hs, c0, tlo, thi);
    mega_k<<<SEGS, 512, 0, stream>>>(x4, (float4*)d_out, n4, xbits, (float*)d_out, N,
                                     c0, seg_cnt, cand);
    cand13_k<<<SEGS, 256, 0, stream>>>(cand, seg_cnt, c0, h13c);
    scan13c_k<<<1, 1024, 0, stream>>>(h13c, c0, k0);
    cand18_k<<<SEGS, 256, 0, stream>>>(cand, seg_cnt, c0, h18);
    scan_big1_k<<<256, 256, 0, stream>>>(h18, chunkSums);
    scan18t_k<<<1, 1024, 0, stream>>>(h18, chunkSums, c0);
    fixup_k<<<SEGS, 256, 0, stream>>>(cand, seg_cnt, c0, (float*)d_out);
    // gated repair chain (early-exit when flag==0)
    r13_k<<<2048, 256, 0, stream>>>(x4, n4, xbits, N, h13r, c0);
    rscan13_k<<<1, 1024, 0, stream>>>(h13r, c0, k0);
    rh18_k<<<2048, 256, 0, stream>>>(x4, n4, xbits, N, h18r, c0);
    rs18_k<<<1, 1024, 0, stream>>>(h18r, c0);
    rmask_k<<<2048, 256, 0, stream>>>((const float4*)x, (float4*)d_out, n4,
                                      x, (float*)d_out, N, c0);
    return;
  }

  // ---------- fallback: two-full-hist structure with kernel zeroing ----------
  const size_t needA = 65536 + (size_t)(1u << 19) * 4;  // 2,162,688
  char* wsb = (char*)d_ws;
  char* arena = (ws_size >= needA) ? wsb : (char*)d_out;  // d_out fully rewritten at end
  Ctrl* c0 = (ws_size >= 128) ? (Ctrl*)wsb : (Ctrl*)arena;
  Ctrl* c1 = c0 + 1;
  unsigned* chunkSums = (unsigned*)(arena + 128);
  unsigned* h1 = (unsigned*)(arena + 4096);
  unsigned* h2 = (unsigned*)(arena + 65536);
  const long long zwords = (long long)(needA - 4096) / 4;

  zero_words_k<<<512, 256, 0, stream>>>((unsigned*)(arena + 4096), zwords);
  init_ctrl_k<<<1, 64, 0, stream>>>(c0, k0, (dual ? c1 : c0), k1);

  const int nchain = dual ? 2 : 1;
  for (int chain = 0; chain < nchain; ++chain) {
    Ctrl* cc = chain ? c1 : c0;
    if (chain) zero_words_k<<<512, 256, 0, stream>>>((unsigned*)(arena + 4096), zwords);
    hist_stage_k<<<2048, 256, 0, stream>>>(x4, n4, xbits, N, h1, cc, 19, 12);
    scan_stage_k<<<1, 1024, 0, stream>>>(h1, 12, cc);
    hist_stage_k<<<2048, 256, 0, stream>>>(x4, n4, xbits, N, h2, cc, 0, 19);
    scan_big1_k<<<512, 256, 0, stream>>>(h2, chunkSums);
    scan_big2_k<<<1, 1024, 0, stream>>>(h2, chunkSums, cc);
  }
  combine_thr_k<<<1, 64, 0, stream>>>(c0, (dual ? c1 : c0), lw, hw);
  mask_k<<<2048, 256, 0, stream>>>((const float4*)x, (float4*)d_out, n4,
                                   x, (float*)d_out, N, c0);
}

// Round 7
// 246.709 us; speedup vs baseline: 47.5356x; 1.0914x over previous
//
#include <hip/hip_runtime.h>
#include <stdint.h>

// Exact global median-of-|x| + masked copy, one full-data pass.
// thr replicates jnp fp32 semantics: thr = (t*0.1f)/0.1f (RN).
//
// Fast path (ws >= ~22MB):
//   S1a: sampled 13-bit hist (16MB read) -> coarse interval [blo,bhi]
//   S1b: sampled sub-bin hist over that interval (re-read 16MB, L3-hit)
//        -> tight key interval [Klo,Khi) (~154K keys, 12-sigma + 4-ulp pads)
//   S2 : MEGA pass (read 360MB + nt-write 360MB): classify by 2 compares,
//        exact below-count, segment-compact ~0.5M candidates
//   S3 : ulp-exact select: h20[key-Klo] hist -> chunk sums -> scan -> thr;
//        gated fixup scatters survivors
//   S4 : exactness: invariants verified in scan20 else flag -> gated repair
//        chain (5 early-exit kernels) recomputes select+mask from full data.
// Fallback (small N / small ws / interpolated quantile): two-full-hist select.

struct Ctrl {
  unsigned prefix;   // selected key (or repair 13-bit bin)
  unsigned rank;     // remaining rank (repair path)
  float    thr;      // final threshold
  unsigned ovf;      // overflow candidate count
  unsigned below;    // exact count of keys < klo
  unsigned blo;      // stage-1 low bin  (atomicMax)
  unsigned bhi;      // stage-1 high bin (atomicMin)
  unsigned flag;     // repair needed
  unsigned klo;      // final candidate interval [klo, khi)
  unsigned khi;
  unsigned kloA;     // stage-1 interval key base
  unsigned khiA;     // stage-1 interval key end (exclusive)
  unsigned s2;       // stage-2 sub-bin shift
  unsigned slo;      // stage-2 low sub-bin  (atomicMax)
  unsigned shi;      // stage-2 high sub-bin (atomicMin)
  unsigned pad;
};

typedef float fx4 __attribute__((ext_vector_type(4)));

#define SEGS   1024u
#define SEGCAP 2048u
#define OCAP   131072u

// Arena word offsets:
#define W_HS     32u        // stage-1 sample hist (8192)
#define W_HS2    8224u      // stage-2 sample hist (8192)
#define W_SEGCNT 16416u     // seg_cnt (1024)
#define W_CHUNK  17440u     // chunkSums (512)
#define W_H20    32768u     // ulp hist (2^19)
#define W_H13R   557056u    // repair 13-bit (8192)   [lazily zeroed]
#define W_H18R   565248u    // repair 18-bit (262144) [lazily zeroed]
#define ZERO_WORDS 557056u
#define CAND_BYTE_OFF 4194304u

// ---------------- small shared kernels ----------------

__global__ __launch_bounds__(256) void zero_words_k(unsigned* __restrict__ p, long long nwords) {
  long long i = (long long)blockIdx.x * blockDim.x + threadIdx.x;
  long long s = (long long)gridDim.x * blockDim.x;
  for (; i < nwords; i += s) p[i] = 0u;
}

__global__ __launch_bounds__(64) void init_ctrl_k(Ctrl* c0, unsigned k0,
                                                  Ctrl* c1, unsigned k1) {
  if (threadIdx.x == 0 && blockIdx.x == 0) {
    c0->prefix = 0u; c0->rank = k0; c0->thr = 0.0f; c0->ovf = 0u;
    c1->prefix = 0u; c1->rank = k1; c1->thr = 0.0f; c1->ovf = 0u;
  }
}

__global__ __launch_bounds__(64) void combine_thr_k(Ctrl* a, const Ctrl* b,
                                                    float lw, float hw) {
  if (threadIdx.x == 0 && blockIdx.x == 0) {
    float v0 = __uint_as_float(a->prefix);
    float v1 = __uint_as_float(b->prefix);
    float tq = __fadd_rn(__fmul_rn(v0, lw), __fmul_rn(v1, hw));
    a->thr = __fdiv_rn(__fmul_rn(tq, 0.1f), 0.1f);
  }
}

// ---------------- fast path ----------------

__global__ __launch_bounds__(256) void setup_k(unsigned* arena, unsigned k0) {
  const unsigned gstr = gridDim.x * 256u;
  for (unsigned i = blockIdx.x * 256u + threadIdx.x; i < ZERO_WORDS; i += gstr)
    arena[i] = 0u;
  if (blockIdx.x == 0) {
    __syncthreads();
    if (threadIdx.x == 0) {
      Ctrl* c = (Ctrl*)arena;
      c->rank = k0;
      c->bhi = 8191u;      // atomicMin targets
      c->shi = 8191u;
    }
  }
}

// S1a: sampled 13-bit hist. 4096 chunks x 1024 floats (16MB, 4.19M samples).
__global__ __launch_bounds__(256) void sample13_k(
    const uint4* __restrict__ x4, long long n4, unsigned* __restrict__ hs)
{
  __shared__ unsigned lh[8192];
  for (unsigned i = threadIdx.x; i < 8192u; i += 256u) lh[i] = 0u;
  __syncthreads();
  const long long cstride = n4 >> 12;
  for (unsigned j = 0; j < 16u; ++j) {
    unsigned c = blockIdx.x * 16u + j;
    long long idx = (long long)c * cstride + threadIdx.x;
    if (idx < n4) {
      uint4 v = x4[idx];
      atomicAdd(&lh[(v.x & 0x7fffffffu) >> 18], 1u);
      atomicAdd(&lh[(v.y & 0x7fffffffu) >> 18], 1u);
      atomicAdd(&lh[(v.z & 0x7fffffffu) >> 18], 1u);
      atomicAdd(&lh[(v.w & 0x7fffffffu) >> 18], 1u);
    }
  }
  __syncthreads();
  for (unsigned j = threadIdx.x; j < 8192u; j += 256u) {
    unsigned s = lh[j];
    if (s) atomicAdd(&hs[j], s);
  }
}

// S1a-scan: coarse interval [blo,bhi] + finalize kloA/khiA/s2.
__global__ __launch_bounds__(1024) void sscan_k(
    const unsigned* __restrict__ h, Ctrl* __restrict__ ctrl,
    unsigned tlo, unsigned thi)
{
  __shared__ unsigned wsum[16], wbase[16];
  const unsigned t = threadIdx.x, lane = t & 63u, wid = t >> 6;
  const unsigned lo = t * 8u, hi = lo + 8u;
  unsigned s = 0;
  for (unsigned j = lo; j < hi; ++j) s += h[j];
  unsigned run = s;
  for (unsigned o = 1; o < 64; o <<= 1) {
    unsigned v = __shfl_up(run, o, 64);
    if (lane >= o) run += v;
  }
  if (lane == 63u) wsum[wid] = run;
  __syncthreads();
  if (t == 0) { unsigned acc = 0; for (int i = 0; i < 16; ++i) { wbase[i] = acc; acc += wsum[i]; } }
  __syncthreads();
  unsigned c = wbase[wid] + run - s;
  int myblo = -1, mybhi = -1;
  for (unsigned j = lo; j < hi; ++j) {
    unsigned excl = c;
    c += h[j];
    if (excl < tlo) myblo = (int)j;
    if (mybhi < 0 && c > thi) mybhi = (int)j;
  }
  if (myblo >= 0) atomicMax(&ctrl->blo, (unsigned)myblo);
  if (mybhi >= 0) atomicMin(&ctrl->bhi, (unsigned)mybhi);
  __syncthreads();
  if (t == 0) {
    unsigned blo = ctrl->blo, bhi = ctrl->bhi;
    if (bhi < blo) bhi = blo;
    unsigned rangeA = (bhi - blo + 1u) << 18;
    unsigned sh = 0;
    while ((rangeA >> sh) > 8192u) ++sh;
    ctrl->bhi = bhi;
    ctrl->kloA = blo << 18;
    ctrl->khiA = (blo << 18) + rangeA;
    ctrl->s2 = sh;
  }
}

// S1b: stage-2 sampled sub-bin hist over [kloA,khiA) (same 16MB, L3-hit).
__global__ __launch_bounds__(256) void sample2_k(
    const uint4* __restrict__ x4, long long n4,
    const Ctrl* __restrict__ ctrl, unsigned* __restrict__ hs2)
{
  __shared__ unsigned lh[8192];
  for (unsigned i = threadIdx.x; i < 8192u; i += 256u) lh[i] = 0u;
  __syncthreads();
  const unsigned kloA = ctrl->kloA, khiA = ctrl->khiA, sh = ctrl->s2;
  const long long cstride = n4 >> 12;
  for (unsigned j = 0; j < 16u; ++j) {
    unsigned c = blockIdx.x * 16u + j;
    long long idx = (long long)c * cstride + threadIdx.x;
    if (idx < n4) {
      uint4 v = x4[idx];
      #pragma unroll
      for (int e = 0; e < 4; ++e) {
        unsigned key = (&v.x)[e] & 0x7fffffffu;
        if (key >= kloA && key < khiA) atomicAdd(&lh[(key - kloA) >> sh], 1u);
      }
    }
  }
  __syncthreads();
  for (unsigned j = threadIdx.x; j < 8192u; j += 256u) {
    unsigned s = lh[j];
    if (s) atomicAdd(&hs2[j], s);
  }
}

// S1b-scan: tight interval [klo,khi) from stage-2 hist.
__global__ __launch_bounds__(1024) void sscan2_k(
    const unsigned* __restrict__ hs, const unsigned* __restrict__ hs2,
    Ctrl* __restrict__ ctrl, unsigned tlo, unsigned thi)
{
  __shared__ unsigned wsum[16], wbase[16];
  __shared__ unsigned sh_cblo;
  const unsigned t = threadIdx.x, lane = t & 63u, wid = t >> 6;
  const unsigned lo = t * 8u, hi = lo + 8u;
  const unsigned blo = ctrl->blo;
  // C_blo = samples strictly below stage-1 bin blo (masked block sum).
  unsigned cb = 0;
  for (unsigned j = lo; j < hi; ++j) if (j < blo) cb += hs[j];
  unsigned r0 = cb;
  for (int o = 32; o > 0; o >>= 1) r0 += __shfl_down(r0, o, 64);
  if (lane == 0) wsum[wid] = r0;
  __syncthreads();
  if (t == 0) { unsigned acc = 0; for (int i = 0; i < 16; ++i) acc += wsum[i]; sh_cblo = acc; }
  __syncthreads();
  const unsigned cblo = sh_cblo;
  const unsigned tlo2 = (tlo > cblo) ? tlo - cblo : 0u;
  const unsigned thi2 = (thi > cblo) ? thi - cblo : 0u;
  // scan hs2, pick sub-bin interval
  unsigned s = 0;
  for (unsigned j = lo; j < hi; ++j) s += hs2[j];
  unsigned run = s;
  for (unsigned o = 1; o < 64; o <<= 1) {
    unsigned v = __shfl_up(run, o, 64);
    if (lane >= o) run += v;
  }
  if (lane == 63u) wsum[wid] = run;
  __syncthreads();
  if (t == 0) { unsigned acc = 0; for (int i = 0; i < 16; ++i) { wbase[i] = acc; acc += wsum[i]; } }
  __syncthreads();
  unsigned c = wbase[wid] + run - s;
  int myslo = -1, myshi = -1;
  for (unsigned j = lo; j < hi; ++j) {
    unsigned excl = c;
    c += hs2[j];
    if (excl < tlo2) myslo = (int)j;
    if (myshi < 0 && c > thi2) myshi = (int)j;
  }
  if (myslo >= 0) atomicMax(&ctrl->slo, (unsigned)myslo);
  if (myshi >= 0) atomicMin(&ctrl->shi, (unsigned)myshi);
  __syncthreads();
  if (t == 0) {
    unsigned slo = ctrl->slo, shi = ctrl->shi;
    if (shi < slo) shi = slo;
    const unsigned kloA = ctrl->kloA, sh = ctrl->s2;
    unsigned klo = kloA + (slo << sh);
    klo = (klo >= 4u) ? klo - 4u : 0u;
    unsigned long long khi64 = (unsigned long long)kloA + ((unsigned long long)(shi + 1u) << sh) + 4ull;
    unsigned khi = (khi64 < 0x7fffffffull) ? (unsigned)khi64 : 0x7fffffffu;
    ctrl->klo = klo;
    ctrl->khi = khi;
  }
}

// S2: the single full pass. Classify, count below, compact candidates.
__global__ __launch_bounds__(512) void mega_k(
    const uint4* __restrict__ x4, float4* __restrict__ o4, long long n4,
    const unsigned* __restrict__ xs, float* __restrict__ os, long long n,
    Ctrl* __restrict__ ctrl, unsigned* __restrict__ seg_cnt,
    uint2* __restrict__ cand)
{
  __shared__ unsigned lcnt;
  __shared__ unsigned wred[8];
  if (threadIdx.x == 0) lcnt = 0u;
  __syncthreads();
  const unsigned Klo = ctrl->klo, Khi = ctrl->khi;
  uint2* __restrict__ seg = cand + (size_t)blockIdx.x * SEGCAP;
  uint2* __restrict__ ovf = cand + (size_t)SEGS * SEGCAP;
  unsigned below = 0;
  const long long stride = (long long)gridDim.x * blockDim.x;
  for (long long i = (long long)blockIdx.x * blockDim.x + threadIdx.x; i < n4; i += stride) {
    uint4 v = x4[i];
    unsigned bidx = (unsigned)(i * 4);
    fx4 w;
    #pragma unroll
    for (int c = 0; c < 4; ++c) {
      unsigned raw = (&v.x)[c];
      unsigned key = raw & 0x7fffffffu;
      float val = __uint_as_float(raw);
      bool keep = key >= Khi;
      w[c] = keep ? val : 0.0f;
      if (key < Klo) below++;
      else if (!keep) {
        unsigned pos = atomicAdd(&lcnt, 1u);
        uint2 e; e.x = raw; e.y = bidx + (unsigned)c;
        if (pos < SEGCAP) seg[pos] = e;
        else { unsigned op = atomicAdd(&ctrl->ovf, 1u); if (op < OCAP) ovf[op] = e; }
      }
    }
    __builtin_nontemporal_store(w, (fx4*)&o4[i]);
  }
  for (long long t = n4 * 4 + (long long)blockIdx.x * blockDim.x + threadIdx.x; t < n; t += stride) {
    unsigned raw = xs[t];
    unsigned key = raw & 0x7fffffffu;
    float val = __uint_as_float(raw);
    bool keep = key >= Khi;
    os[t] = keep ? val : 0.0f;
    if (key < Klo) below++;
    else if (!keep) {
      unsigned pos = atomicAdd(&lcnt, 1u);
      uint2 e; e.x = raw; e.y = (unsigned)t;
      if (pos < SEGCAP) seg[pos] = e;
      else { unsigned op = atomicAdd(&ctrl->ovf, 1u); if (op < OCAP) ovf[op] = e; }
    }
  }
  for (int o = 32; o > 0; o >>= 1) below += __shfl_down(below, o, 64);
  if ((threadIdx.x & 63u) == 0u) wred[threadIdx.x >> 6] = below;
  __syncthreads();
  if (threadIdx.x == 0) {
    unsigned s = 0;
    for (int i = 0; i < 8; ++i) s += wred[i];
    atomicAdd(&ctrl->below, s);
    seg_cnt[blockIdx.x] = (lcnt < SEGCAP) ? lcnt : SEGCAP;
  }
}

// S3a: ulp-resolution hist of candidates: h20[key - klo].
__global__ __launch_bounds__(256) void cand20_k(
    const uint2* __restrict__ cand, const unsigned* __restrict__ seg_cnt,
    const Ctrl* __restrict__ ctrl, unsigned* __restrict__ h20)
{
  const unsigned klo = ctrl->klo;
  const uint2* __restrict__ seg = cand + (size_t)blockIdx.x * SEGCAP;
  unsigned cnt = seg_cnt[blockIdx.x];
  for (unsigned t = threadIdx.x; t < cnt; t += 256u) {
    unsigned idx = (seg[t].x & 0x7fffffffu) - klo;
    if (idx < (1u << 19)) atomicAdd(&h20[idx], 1u);
  }
  if (blockIdx.x == 0) {
    unsigned oc = ctrl->ovf; if (oc > OCAP) oc = OCAP;
    const uint2* __restrict__ ovf = cand + (size_t)SEGS * SEGCAP;
    for (unsigned t = threadIdx.x; t < oc; t += 256u) {
      unsigned idx = (ovf[t].x & 0x7fffffffu) - klo;
      if (idx < (1u << 19)) atomicAdd(&h20[idx], 1u);
    }
  }
}

// chunk sums (grid = nbins/1024 blocks).
__global__ __launch_bounds__(256) void scan_big1_k(
    const unsigned* __restrict__ hist, unsigned* __restrict__ chunkSums)
{
  __shared__ unsigned red[256];
  const unsigned base = blockIdx.x * 1024u;
  unsigned s = 0;
  for (unsigned i = threadIdx.x; i < 1024u; i += 256u) s += hist[base + i];
  red[threadIdx.x] = s;
  __syncthreads();
  for (unsigned off = 128; off > 0; off >>= 1) {
    if (threadIdx.x < off) red[threadIdx.x] += red[threadIdx.x + off];
    __syncthreads();
  }
  if (threadIdx.x == 0) chunkSums[blockIdx.x] = red[0];
}

// S3b: ulp-exact select + thr + invariant verification (+ lazy repair zero).
__global__ __launch_bounds__(1024) void scan20_k(
    const unsigned* __restrict__ h20, const unsigned* __restrict__ cs,
    Ctrl* __restrict__ ctrl, unsigned k0,
    unsigned* __restrict__ h13r, unsigned* __restrict__ h18r)
{
  __shared__ unsigned csh[512];
  __shared__ unsigned sc[1024];
  __shared__ unsigned sel[3];
  __shared__ unsigned sh_key, sh_found, sh_bad;
  const unsigned t = threadIdx.x;
  if (t == 0) { sh_found = 0u; sh_bad = 0u; }
  if (t < 512) csh[t] = cs[t];
  __syncthreads();
  const unsigned klo = ctrl->klo, khi = ctrl->khi;
  const unsigned below = ctrl->below, ovf = ctrl->ovf;
  const unsigned range = khi - klo;
  const unsigned rc = k0 - below;     // may wrap; verified below
  if (t == 0) {
    unsigned run = 0, ci = 0, cb = 0;
    for (int i = 0; i < 512; ++i) {
      unsigned cnt = csh[i];
      if (rc >= run && rc < run + cnt) { ci = (unsigned)i; cb = run; }
      run += cnt;
    }
    sel[0] = ci; sel[1] = cb; sel[2] = run;   // run = total
  }
  __syncthreads();
  const unsigned ci = sel[0], cb = sel[1], total = sel[2];
  unsigned val = h20[ci * 1024u + t];
  sc[t] = val;
  __syncthreads();
  for (unsigned off = 1; off < 1024; off <<= 1) {
    unsigned add = (t >= off) ? sc[t - off] : 0u;
    __syncthreads();
    sc[t] += add;
    __syncthreads();
  }
  const unsigned incl = sc[t], excl = incl - val;
  const unsigned rr = rc - cb;
  if (val > 0 && rc < total && rr >= excl && rr < incl) {
    unsigned key = klo + ci * 1024u + t;
    sh_key = key; sh_found = 1u;
    if (key < klo + 4u || key + 4u >= khi) sh_bad = 1u;
  }
  __syncthreads();
  if (t == 0) {
    bool bad = (k0 < below) || (rc >= total) || (ovf > OCAP) ||
               (range > (1u << 19)) || (sh_found == 0u) || (sh_bad != 0u);
    if (!bad) {
      unsigned key = sh_key;
      float v = __uint_as_float(key);
      ctrl->thr = __fdiv_rn(__fmul_rn(v, 0.1f), 0.1f);
      ctrl->prefix = key;
      sel[0] = 0u;
    } else sel[0] = 1u;
  }
  __syncthreads();
  if (sel[0]) {
    for (unsigned i = t; i < 8192u; i += 1024u) h13r[i] = 0u;
    for (unsigned i = t; i < 262144u; i += 1024u) h18r[i] = 0u;
    __syncthreads();
    if (t == 0) ctrl->flag = 1u;
  }
}

// S3c: scatter-fix surviving candidates (skipped when repair flagged).
__global__ __launch_bounds__(256) void fixup_k(
    const uint2* __restrict__ cand, const unsigned* __restrict__ seg_cnt,
    const Ctrl* __restrict__ ctrl, float* __restrict__ out)
{
  if (*(volatile const unsigned*)&ctrl->flag != 0u) return;
  const float thr = ctrl->thr;
  const uint2* __restrict__ seg = cand + (size_t)blockIdx.x * SEGCAP;
  unsigned cnt = seg_cnt[blockIdx.x];
  for (unsigned t = threadIdx.x; t < cnt; t += 256u) {
    uint2 e = seg[t];
    float v = __uint_as_float(e.x);
    if (fabsf(v) > thr) out[e.y] = v;
  }
  if (blockIdx.x == 0) {
    unsigned oc = ctrl->ovf; if (oc > OCAP) oc = OCAP;
    const uint2* __restrict__ ovf = cand + (size_t)SEGS * SEGCAP;
    for (unsigned t = threadIdx.x; t < oc; t += 256u) {
      uint2 e = ovf[t];
      float v = __uint_as_float(e.x);
      if (fabsf(v) > thr) out[e.y] = v;
    }
  }
}

// ---------------- gated repair chain (exactness guarantee) ----------------

__global__ __launch_bounds__(256) void r13_k(
    const uint4* __restrict__ x4, long long n4,
    const unsigned* __restrict__ xs, long long n,
    unsigned* __restrict__ h13r, const Ctrl* __restrict__ ctrl)
{
  if (*(volatile const unsigned*)&ctrl->flag == 0u) return;
  __shared__ unsigned lh[8192];
  for (unsigned i = threadIdx.x; i < 8192u; i += 256u) lh[i] = 0u;
  __syncthreads();
  const long long stride = (long long)gridDim.x * blockDim.x;
  for (long long i = (long long)blockIdx.x * blockDim.x + threadIdx.x; i < n4; i += stride) {
    uint4 v = x4[i];
    atomicAdd(&lh[(v.x & 0x7fffffffu) >> 18], 1u);
    atomicAdd(&lh[(v.y & 0x7fffffffu) >> 18], 1u);
    atomicAdd(&lh[(v.z & 0x7fffffffu) >> 18], 1u);
    atomicAdd(&lh[(v.w & 0x7fffffffu) >> 18], 1u);
  }
  for (long long t = n4 * 4 + (long long)blockIdx.x * blockDim.x + threadIdx.x; t < n; t += stride)
    atomicAdd(&lh[(xs[t] & 0x7fffffffu) >> 18], 1u);
  __syncthreads();
  for (unsigned j = threadIdx.x; j < 8192u; j += 256u) {
    unsigned s = lh[j];
    if (s) atomicAdd(&h13r[j], s);
  }
}

__global__ __launch_bounds__(1024) void rscan13_k(
    const unsigned* __restrict__ h, Ctrl* __restrict__ ctrl, unsigned k0)
{
  if (*(volatile const unsigned*)&ctrl->flag == 0u) return;
  __shared__ unsigned wsum[16], wbase[16];
  const unsigned t = threadIdx.x, lane = t & 63u, wid = t >> 6;
  const unsigned lo = t * 8u, hi = lo + 8u;
  unsigned s = 0;
  for (unsigned j = lo; j < hi; ++j) s += h[j];
  unsigned run = s;
  for (unsigned o = 1; o < 64; o <<= 1) {
    unsigned v = __shfl_up(run, o, 64);
    if (lane >= o) run += v;
  }
  if (lane == 63u) wsum[wid] = run;
  __syncthreads();
  if (t == 0) { unsigned acc = 0; for (int i = 0; i < 16; ++i) { wbase[i] = acc; acc += wsum[i]; } }
  __syncthreads();
  const unsigned base = wbase[wid] + run - s;
  if (s > 0 && k0 >= base && k0 < base + s) {
    unsigned c = base;
    for (unsigned j = lo; j < hi; ++j) {
      unsigned cnt = h[j];
      if (k0 < c + cnt) { ctrl->prefix = j; ctrl->rank = k0 - c; break; }
      c += cnt;
    }
  }
}

__global__ __launch_bounds__(256) void rh18_k(
    const uint4* __restrict__ x4, long long n4,
    const unsigned* __restrict__ xs, long long n,
    unsigned* __restrict__ h18r, const Ctrl* __restrict__ ctrl)
{
  if (*(volatile const unsigned*)&ctrl->flag == 0u) return;
  const unsigned prefix = ctrl->prefix;
  const long long stride = (long long)gridDim.x * blockDim.x;
  for (long long i = (long long)blockIdx.x * blockDim.x + threadIdx.x; i < n4; i += stride) {
    uint4 v = x4[i];
    unsigned a = v.x & 0x7fffffffu, b = v.y & 0x7fffffffu;
    unsigned c = v.z & 0x7fffffffu, d = v.w & 0x7fffffffu;
    if ((a >> 18) == prefix) atomicAdd(&h18r[a & 0x3ffffu], 1u);
    if ((b >> 18) == prefix) atomicAdd(&h18r[b & 0x3ffffu], 1u);
    if ((c >> 18) == prefix) atomicAdd(&h18r[c & 0x3ffffu], 1u);
    if ((d >> 18) == prefix) atomicAdd(&h18r[d & 0x3ffffu], 1u);
  }
  for (long long t = n4 * 4 + (long long)blockIdx.x * blockDim.x + threadIdx.x; t < n; t += stride) {
    unsigned u = xs[t] & 0x7fffffffu;
    if ((u >> 18) == prefix) atomicAdd(&h18r[u & 0x3ffffu], 1u);
  }
}

__global__ __launch_bounds__(1024) void rs18_k(
    const unsigned* __restrict__ h, Ctrl* __restrict__ ctrl)
{
  if (*(volatile const unsigned*)&ctrl->flag == 0u) return;
  __shared__ unsigned wsum[16], wbase[16];
  const unsigned t = threadIdx.x, lane = t & 63u, wid = t >> 6;
  const unsigned lo = t * 256u, hi = lo + 256u;
  const unsigned oldP = ctrl->prefix;
  const unsigned r = ctrl->rank;
  unsigned s = 0;
  for (unsigned j = lo; j < hi; ++j) s += h[j];
  unsigned run = s;
  for (unsigned o = 1; o < 64; o <<= 1) {
    unsigned v = __shfl_up(run, o, 64);
    if (lane >= o) run += v;
  }
  if (lane == 63u) wsum[wid] = run;
  __syncthreads();
  if (t == 0) { unsigned acc = 0; for (int i = 0; i < 16; ++i) { wbase[i] = acc; acc += wsum[i]; } }
  __syncthreads();
  const unsigned base = wbase[wid] + run - s;
  if (s > 0 && r >= base && r < base + s) {
    unsigned c = base;
    for (unsigned j = lo; j < hi; ++j) {
      unsigned cnt = h[j];
      if (r < c + cnt) {
        unsigned key = (oldP << 18) | j;
        float v = __uint_as_float(key);
        ctrl->thr = __fdiv_rn(__fmul_rn(v, 0.1f), 0.1f);
        ctrl->prefix = key;
        break;
      }
      c += cnt;
    }
  }
}

__global__ __launch_bounds__(256) void rmask_k(
    const float4* __restrict__ x4, float4* __restrict__ o4, long long n4,
    const float* __restrict__ xs, float* __restrict__ os, long long n,
    const Ctrl* __restrict__ ctrl)
{
  if (*(volatile const unsigned*)&ctrl->flag == 0u) return;
  const float thr = ctrl->thr;
  const long long stride = (long long)gridDim.x * blockDim.x;
  for (long long i = (long long)blockIdx.x * blockDim.x + threadIdx.x; i < n4; i += stride) {
    float4 v = x4[i];
    fx4 w;
    w[0] = (fabsf(v.x) <= thr) ? 0.0f : v.x;
    w[1] = (fabsf(v.y) <= thr) ? 0.0f : v.y;
    w[2] = (fabsf(v.z) <= thr) ? 0.0f : v.z;
    w[3] = (fabsf(v.w) <= thr) ? 0.0f : v.w;
    __builtin_nontemporal_store(w, (fx4*)&o4[i]);
  }
  for (long long t = n4 * 4 + (long long)blockIdx.x * blockDim.x + threadIdx.x; t < n; t += stride) {
    float v = xs[t];
    os[t] = (fabsf(v) <= thr) ? 0.0f : v;
  }
}

// ---------------- fallback path ----------------

__global__ __launch_bounds__(1024) void scan_stage_k(
    const unsigned* __restrict__ hist, int bits, Ctrl* __restrict__ ctrl)
{
  __shared__ unsigned wsum[16], wbase[16];
  const unsigned nb = 1u << bits;
  const unsigned per = (nb + 1023u) >> 10;
  const unsigned t = threadIdx.x, lane = t & 63u, wid = t >> 6;
  const unsigned lo = t * per;
  const unsigned hi = (lo + per < nb) ? (lo + per) : nb;
  const unsigned oldPrefix = ctrl->prefix;
  const unsigned r = ctrl->rank;
  unsigned s = 0;
  for (unsigned j = lo; j < hi; ++j) s += hist[j];
  unsigned run = s;
  for (unsigned o = 1; o < 64; o <<= 1) {
    unsigned v = __shfl_up(run, o, 64);
    if (lane >= o) run += v;
  }
  if (lane == 63u) wsum[wid] = run;
  __syncthreads();
  if (t == 0) { unsigned acc = 0; for (int i = 0; i < 16; ++i) { wbase[i] = acc; acc += wsum[i]; } }
  __syncthreads();
  const unsigned base = wbase[wid] + run - s;
  if (s > 0 && r >= base && r < base + s) {
    unsigned c = base;
    for (unsigned j = lo; j < hi; ++j) {
      unsigned cnt = hist[j];
      if (r < c + cnt) {
        ctrl->prefix = (oldPrefix << bits) | j;
        ctrl->rank = r - c;
        break;
      }
      c += cnt;
    }
  }
}

__global__ __launch_bounds__(256) void hist_stage_k(
    const uint4* __restrict__ x4, long long n4,
    const unsigned* __restrict__ xs, long long n,
    unsigned* __restrict__ hist,
    const Ctrl* __restrict__ ctrl,
    int shift, int bits)
{
  __shared__ unsigned lh[4096];
  const unsigned nb = 1u << bits;
  const bool lds = (bits <= 12);
  if (lds) {
    for (unsigned i = threadIdx.x; i < nb; i += blockDim.x) lh[i] = 0u;
    __syncthreads();
  }
  const unsigned prefix = ctrl->prefix;
  const int top = shift + bits;
  const unsigned m = nb - 1u;
  const long long stride = (long long)gridDim.x * blockDim.x;
  long long i = (long long)blockIdx.x * blockDim.x + threadIdx.x;
  for (; i < n4; i += stride) {
    uint4 v = x4[i];
    unsigned a = v.x & 0x7fffffffu;
    unsigned b = v.y & 0x7fffffffu;
    unsigned c = v.z & 0x7fffffffu;
    unsigned d = v.w & 0x7fffffffu;
    if (lds) {
      if ((a >> top) == prefix) atomicAdd(&lh[(a >> shift) & m], 1u);
      if ((b >> top) == prefix) atomicAdd(&lh[(b >> shift) & m], 1u);
      if ((c >> top) == prefix) atomicAdd(&lh[(c >> shift) & m], 1u);
      if ((d >> top) == prefix) atomicAdd(&lh[(d >> shift) & m], 1u);
    } else {
      if ((a >> top) == prefix) atomicAdd(&hist[(a >> shift) & m], 1u);
      if ((b >> top) == prefix) atomicAdd(&hist[(b >> shift) & m], 1u);
      if ((c >> top) == prefix) atomicAdd(&hist[(c >> shift) & m], 1u);
      if ((d >> top) == prefix) atomicAdd(&hist[(d >> shift) & m], 1u);
    }
  }
  long long t = n4 * 4 + (long long)blockIdx.x * blockDim.x + threadIdx.x;
  for (; t < n; t += stride) {
    unsigned u = xs[t] & 0x7fffffffu;
    if ((u >> top) == prefix) {
      if (lds) atomicAdd(&lh[(u >> shift) & m], 1u);
      else     atomicAdd(&hist[(u >> shift) & m], 1u);
    }
  }
  if (lds) {
    __syncthreads();
    for (unsigned j = threadIdx.x; j < nb; j += blockDim.x) {
      unsigned cv = lh[j];
      if (cv) atomicAdd(&hist[j], cv);
    }
  }
}

__global__ __launch_bounds__(1024) void scan_big2_k(
    const unsigned* __restrict__ hist, const unsigned* __restrict__ chunkSums,
    Ctrl* __restrict__ ctrl)
{
  __shared__ unsigned cs[512];
  __shared__ unsigned sc[1024];
  __shared__ unsigned sel[2];
  const unsigned t = threadIdx.x;
  const unsigned oldPrefix = ctrl->prefix;
  const unsigned r = ctrl->rank;
  if (t < 512) cs[t] = chunkSums[t];
  __syncthreads();
  if (t == 0) {
    unsigned run = 0, ci = 0, cb = 0;
    for (int i = 0; i < 512; ++i) {
      unsigned cnt = cs[i];
      if (r >= run && r < run + cnt) { ci = (unsigned)i; cb = run; }
      run += cnt;
    }
    sel[0] = ci; sel[1] = cb;
  }
  __syncthreads();
  const unsigned ci = sel[0], cb = sel[1];
  const unsigned val = hist[ci * 1024u + t];
  sc[t] = val;
  __syncthreads();
  for (unsigned off = 1; off < 1024; off <<= 1) {
    unsigned add = (t >= off) ? sc[t - off] : 0u;
    __syncthreads();
    sc[t] += add;
    __syncthreads();
  }
  const unsigned incl = sc[t];
  const unsigned excl = incl - val;
  const unsigned rr = r - cb;
  if (val > 0 && rr >= excl && rr < incl) {
    ctrl->prefix = (oldPrefix << 19) | (ci * 1024u + t);
    ctrl->rank = rr - excl;
  }
}

__global__ __launch_bounds__(256) void mask_k(
    const float4* __restrict__ x4, float4* __restrict__ o4, long long n4,
    const float* __restrict__ xs, float* __restrict__ os, long long n,
    const Ctrl* __restrict__ ctrl)
{
  const float thr = ctrl->thr;
  const long long stride = (long long)gridDim.x * blockDim.x;
  long long i = (long long)blockIdx.x * blockDim.x + threadIdx.x;
  for (; i < n4; i += stride) {
    float4 v = x4[i];
    float4 w;
    w.x = (fabsf(v.x) <= thr) ? 0.0f : v.x;
    w.y = (fabsf(v.y) <= thr) ? 0.0f : v.y;
    w.z = (fabsf(v.z) <= thr) ? 0.0f : v.z;
    w.w = (fabsf(v.w) <= thr) ? 0.0f : v.w;
    o4[i] = w;
  }
  long long t = n4 * 4 + (long long)blockIdx.x * blockDim.x + threadIdx.x;
  for (; t < n; t += stride) {
    float v = xs[t];
    os[t] = (fabsf(v) <= thr) ? 0.0f : v;
  }
}

// ---------------- launch ----------------

extern "C" void kernel_launch(void* const* d_in, const int* in_sizes, int n_in,
                              void* d_out, int out_size, void* d_ws, size_t ws_size,
                              hipStream_t stream)
{
  const float* x = (const float*)d_in[0];
  const long long N = (long long)in_sizes[0];
  const long long n4 = N >> 2;
  const uint4* x4 = (const uint4*)x;
  const unsigned* xbits = (const unsigned*)x;

  // jnp.quantile fp32 index math: idx = 0.5f * f32(N-1).
  float idxf = 0.5f * (float)(N - 1);
  float lowf = floorf(idxf);
  float highf = ceilf(idxf);
  float hw = idxf - lowf;
  float lw = 1.0f - hw;
  unsigned k0 = (unsigned)lowf;
  unsigned k1 = (unsigned)highf;
  int dual = (hw != 0.0f);
  if (!dual) k1 = k0;

  const size_t needC = CAND_BYTE_OFF + ((size_t)SEGS * SEGCAP + OCAP) * 8;  // ~22 MB

  if (!dual && N < (1ll << 32) && n4 >= (1ll << 20) && ws_size >= needC) {
    unsigned* arena = (unsigned*)d_ws;
    Ctrl* c0 = (Ctrl*)arena;
    unsigned* hs        = arena + W_HS;
    unsigned* hs2       = arena + W_HS2;
    unsigned* seg_cnt   = arena + W_SEGCNT;
    unsigned* chunkSums = arena + W_CHUNK;
    unsigned* h20       = arena + W_H20;
    unsigned* h13r      = arena + W_H13R;
    unsigned* h18r      = arena + W_H18R;
    uint2* cand = (uint2*)((char*)d_ws + CAND_BYTE_OFF);

    // sample-count target & 12-sigma margin (ns = 4096*256*4)
    const unsigned long long ns = 4194304ull;
    unsigned target = (unsigned)(((unsigned long long)k0 * ns) / (unsigned long long)N);
    const unsigned m = 12u * 1024u + 32u;
    unsigned tlo = (target > m) ? target - m : 0u;
    unsigned thi = target + m;

    setup_k<<<512, 256, 0, stream>>>(arena, k0);
    sample13_k<<<256, 256, 0, stream>>>(x4, n4, hs);
    sscan_k<<<1, 1024, 0, stream>>>(hs, c0, tlo, thi);
    sample2_k<<<256, 256, 0, stream>>>(x4, n4, c0, hs2);
    sscan2_k<<<1, 1024, 0, stream>>>(hs, hs2, c0, tlo, thi);
    mega_k<<<SEGS, 512, 0, stream>>>(x4, (float4*)d_out, n4, xbits, (float*)d_out, N,
                                     c0, seg_cnt, cand);
    cand20_k<<<SEGS, 256, 0, stream>>>(cand, seg_cnt, c0, h20);
    scan_big1_k<<<512, 256, 0, stream>>>(h20, chunkSums);
    scan20_k<<<1, 1024, 0, stream>>>(h20, chunkSums, c0, k0, h13r, h18r);
    fixup_k<<<SEGS, 256, 0, stream>>>(cand, seg_cnt, c0, (float*)d_out);
    // gated repair chain (early-exit when flag==0)
    r13_k<<<1024, 256, 0, stream>>>(x4, n4, xbits, N, h13r, c0);
    rscan13_k<<<1, 1024, 0, stream>>>(h13r, c0, k0);
    rh18_k<<<1024, 256, 0, stream>>>(x4, n4, xbits, N, h18r, c0);
    rs18_k<<<1, 1024, 0, stream>>>(h18r, c0);
    rmask_k<<<1024, 256, 0, stream>>>((const float4*)x, (float4*)d_out, n4,
                                      x, (float*)d_out, N, c0);
    return;
  }

  // ---------- fallback: two-full-hist structure with kernel zeroing ----------
  const size_t needA = 65536 + (size_t)(1u << 19) * 4;  // 2,162,688
  char* wsb = (char*)d_ws;
  char* arena = (ws_size >= needA) ? wsb : (char*)d_out;  // d_out fully rewritten at end
  Ctrl* c0 = (ws_size >= 128) ? (Ctrl*)wsb : (Ctrl*)arena;
  Ctrl* c1 = c0 + 1;
  unsigned* chunkSums = (unsigned*)(arena + 128);
  unsigned* h1 = (unsigned*)(arena + 4096);
  unsigned* h2 = (unsigned*)(arena + 65536);
  const long long zwords = (long long)(needA - 4096) / 4;

  zero_words_k<<<512, 256, 0, stream>>>((unsigned*)(arena + 4096), zwords);
  init_ctrl_k<<<1, 64, 0, stream>>>(c0, k0, (dual ? c1 : c0), k1);

  const int nchain = dual ? 2 : 1;
  for (int chain = 0; chain < nchain; ++chain) {
    Ctrl* cc = chain ? c1 : c0;
    if (chain) zero_words_k<<<512, 256, 0, stream>>>((unsigned*)(arena + 4096), zwords);
    hist_stage_k<<<2048, 256, 0, stream>>>(x4, n4, xbits, N, h1, cc, 19, 12);
    scan_stage_k<<<1, 1024, 0, stream>>>(h1, 12, cc);
    hist_stage_k<<<2048, 256, 0, stream>>>(x4, n4, xbits, N, h2, cc, 0, 19);
    scan_big1_k<<<512, 256, 0, stream>>>(h2, chunkSums);
    scan_big2_k<<<1, 1024, 0, stream>>>(h2, chunkSums, cc);
  }
  combine_thr_k<<<1, 64, 0, stream>>>(c0, (dual ? c1 : c0), lw, hw);
  mask_k<<<2048, 256, 0, stream>>>((const float4*)x, (float4*)d_out, n4,
                                   x, (float*)d_out, N, c0);
}